// Round 1
// baseline (4558.966 us; speedup 1.0000x reference)
//
#include <hip/hip_runtime.h>

#define N_NODES 16384
#define N_GRAPHS 32
#define NPG 512
#define C 88
#define NL 6
#define NH 4
#define HD 22
#define EA 131072
#define EE 262144
#define EDIM 197
#define EEMB 8
#define PE_RAW 18
#define PE_DIM 10
#define XD 96
#define XF 78
#define BN_EPS 1e-5f
#define ATT_SCALE 0.21320071635561044f
#define INV_N (1.0f / 16384.0f)

// ---------------- edge attr embedding v4: thread/edge, no cross-lane -------
// Skinny GEMM M=(EA+EE), K=197, N=8. One thread per edge, 8 accumulators.
// attr[k] is a per-lane b32 load (row stride 788B; each 64B line reused 16x
// across sequential k -> L1-resident). W row address is wave-uniform ->
// scalarized (s_load) or broadcast. No shuffles, no LDS, no reduction chain.
__global__ __launch_bounds__(256) void k_edge_emb4(const float* __restrict__ Aattr,
                                                   const float* __restrict__ Eattr,
                                                   const float* __restrict__ W,
                                                   float* __restrict__ Aemb,
                                                   float* __restrict__ Eemb) {
    int e = blockIdx.x * 256 + threadIdx.x;   // grid sized exactly: EA+EE = 1536*256
    const float* attr;
    float* dst;
    if (e < EA) {
        attr = Aattr + (size_t)e * EDIM;
        dst = Aemb + (size_t)e * EEMB;
    } else {
        size_t q = (size_t)(e - EA);
        attr = Eattr + q * EDIM;
        dst = Eemb + q * EEMB;
    }
    float acc[8];
#pragma unroll
    for (int j = 0; j < 8; j++) acc[j] = 0.f;
#pragma unroll 4
    for (int k = 0; k < EDIM; k++) {
        float a = attr[k];
        float4 w0 = *(const float4*)(W + (size_t)k * 8);      // uniform addr
        float4 w1 = *(const float4*)(W + (size_t)k * 8 + 4);  // uniform addr
        acc[0] = fmaf(a, w0.x, acc[0]);
        acc[1] = fmaf(a, w0.y, acc[1]);
        acc[2] = fmaf(a, w0.z, acc[2]);
        acc[3] = fmaf(a, w0.w, acc[3]);
        acc[4] = fmaf(a, w1.x, acc[4]);
        acc[5] = fmaf(a, w1.y, acc[5]);
        acc[6] = fmaf(a, w1.z, acc[6]);
        acc[7] = fmaf(a, w1.w, acc[7]);
    }
    // dst = base + e*8 floats -> 32B aligned: two float4 stores.
    *(float4*)(dst) = make_float4(acc[0], acc[1], acc[2], acc[3]);
    *(float4*)(dst + 4) = make_float4(acc[4], acc[5], acc[6], acc[7]);
}

// ---------------- per-column mean/rstd (only for the small PE BN) ----------
__global__ void k_colstats(const float* __restrict__ X, int ldx, int nrows,
                           float* __restrict__ mean, float* __restrict__ rstd) {
    int c = blockIdx.x;
    int t = threadIdx.x;
    float s = 0.f, s2 = 0.f;
    for (int r = t; r < nrows; r += 256) {
        float v = X[(size_t)r * ldx + c];
        s += v; s2 += v * v;
    }
    __shared__ float ls[256], ls2[256];
    ls[t] = s; ls2[t] = s2;
    __syncthreads();
    for (int off = 128; off > 0; off >>= 1) {
        if (t < off) { ls[t] += ls[t + off]; ls2[t] += ls2[t + off]; }
        __syncthreads();
    }
    if (t == 0) {
        float m = ls[0] / nrows;
        float var = ls2[0] / nrows - m * m;
        mean[c] = m;
        rstd[c] = rsqrtf(var + BN_EPS);
    }
}

// ---------------- build h0 = [x, bn(pe)@pe_w + pe_b] -----------------------
__global__ void k_build_h(const float* __restrict__ xd, const float* __restrict__ pe_mean,
                          const float* __restrict__ pe_rstd, const float* __restrict__ pe_g,
                          const float* __restrict__ pe_bt, const float* __restrict__ pe_w,
                          const float* __restrict__ pe_b, float* __restrict__ h) {
    int gid = blockIdx.x * blockDim.x + threadIdx.x;
    if (gid >= N_NODES * C) return;
    int n = gid / C, c = gid % C;
    float v;
    if (c < XF) {
        v = xd[(size_t)n * XD + c];
    } else {
        int j = c - XF;
        float acc = pe_b[j];
#pragma unroll
        for (int i = 0; i < PE_RAW; i++) {
            float pn = (xd[(size_t)n * XD + XF + i] - pe_mean[i]) * pe_rstd[i] * pe_g[i] + pe_bt[i];
            acc += pn * pe_w[i * PE_DIM + j];
        }
        v = acc;
    }
    h[gid] = v;
}

// ---------------- GINE edge message + scatter-add (quad version) -----------
__global__ void k_gine_edge2(const float* __restrict__ Aemb, const int* __restrict__ ei,
                             const float* __restrict__ h, const float* __restrict__ ew,
                             const float* __restrict__ eb, float* __restrict__ aggr) {
    int gid = blockIdx.x * blockDim.x + threadIdx.x;   // e*22 + q
    int e = gid / 22, q = gid % 22;
    const float* emb = Aemb + (size_t)e * EEMB;
    float4 acc = *(const float4*)(eb + 4 * q);
#pragma unroll
    for (int j = 0; j < EEMB; j++) {
        float ej = emb[j];
        float4 w = *(const float4*)(ew + j * C + 4 * q);
        acc.x = fmaf(ej, w.x, acc.x); acc.y = fmaf(ej, w.y, acc.y);
        acc.z = fmaf(ej, w.z, acc.z); acc.w = fmaf(ej, w.w, acc.w);
    }
    int s = ei[e], d = ei[EA + e];
    float4 hv = *(const float4*)(h + (size_t)s * C + 4 * q);
    float* ab = aggr + (size_t)d * C + 4 * q;
    float m0 = fmaxf(acc.x + hv.x, 0.f), m1 = fmaxf(acc.y + hv.y, 0.f);
    float m2 = fmaxf(acc.z + hv.z, 0.f), m3 = fmaxf(acc.w + hv.w, 0.f);
    atomicAdd(ab + 0, m0); atomicAdd(ab + 1, m1);
    atomicAdd(ab + 2, m2); atomicAdd(ab + 3, m3);
}

// ---------------- register-tiled GEMM, no LDS staging ----------------------
// tile: 32 nodes x 88 cols per block; thread = 4 nodes x 4 cols.
// block 192 = 24 col-groups x 8 node-groups (2 col-groups are padding).
// W read b128 from L1 (broadcast across node-groups); X read b128 along K
// (broadcast across col-groups). Optional: X2 added to X, residual R, relu,
// and fused BN raw-moment accumulation into sums[0:88]=sum, sums[88:176]=sumsq.
// z-dim selects (W,b,O) triple for fused q/k/v.
__global__ __launch_bounds__(192) void k_gemm3(const float* __restrict__ X,
                                               const float* __restrict__ X2, int K,
                                               const float* __restrict__ Wa,
                                               const float* __restrict__ Wb,
                                               const float* __restrict__ Wc,
                                               const float* __restrict__ ba,
                                               const float* __restrict__ bb,
                                               const float* __restrict__ bc,
                                               float* __restrict__ Oa,
                                               float* __restrict__ Ob,
                                               float* __restrict__ Oc,
                                               int ldw, int ldo, int relu,
                                               float* __restrict__ sums) {
    __shared__ float red[8 * 192];
    int t = threadIdx.x;
    int z = blockIdx.z;
    const float* W = (z == 0) ? Wa : (z == 1) ? Wb : Wc;
    const float* bias = (z == 0) ? ba : (z == 1) ? bb : bc;
    float* O = (z == 0) ? Oa : (z == 1) ? Ob : Oc;

    int cg = t % 24, nq = t / 24;
    int c4 = 4 * cg;
    int c_off = 88 * blockIdx.y;
    int cidx = c_off + c4;
    int loadc = cidx;
    if (loadc > ldw - 4) loadc = ldw - 4;
    int n0 = blockIdx.x * 32 + 4 * nq;
    const float* Xr = X + (size_t)n0 * K;
    const float* X2r = X2 ? X2 + (size_t)n0 * K : nullptr;

    float4 acc[4];
#pragma unroll
    for (int i = 0; i < 4; i++) acc[i] = make_float4(0.f, 0.f, 0.f, 0.f);

    for (int j = 0; j < K; j += 4) {
        const float* Wr = W + (size_t)j * ldw + loadc;
        float4 w0 = *(const float4*)(Wr);
        float4 w1 = *(const float4*)(Wr + ldw);
        float4 w2 = *(const float4*)(Wr + 2 * ldw);
        float4 w3 = *(const float4*)(Wr + 3 * ldw);
#pragma unroll
        for (int i = 0; i < 4; i++) {
            float4 x = *(const float4*)(Xr + (size_t)i * K + j);
            if (X2r) {
                float4 x2 = *(const float4*)(X2r + (size_t)i * K + j);
                x.x += x2.x; x.y += x2.y; x.z += x2.z; x.w += x2.w;
            }
            acc[i].x = fmaf(x.x, w0.x, acc[i].x); acc[i].y = fmaf(x.x, w0.y, acc[i].y);
            acc[i].z = fmaf(x.x, w0.z, acc[i].z); acc[i].w = fmaf(x.x, w0.w, acc[i].w);
            acc[i].x = fmaf(x.y, w1.x, acc[i].x); acc[i].y = fmaf(x.y, w1.y, acc[i].y);
            acc[i].z = fmaf(x.y, w1.z, acc[i].z); acc[i].w = fmaf(x.y, w1.w, acc[i].w);
            acc[i].x = fmaf(x.z, w2.x, acc[i].x); acc[i].y = fmaf(x.z, w2.y, acc[i].y);
            acc[i].z = fmaf(x.z, w2.z, acc[i].z); acc[i].w = fmaf(x.z, w2.w, acc[i].w);
            acc[i].x = fmaf(x.w, w3.x, acc[i].x); acc[i].y = fmaf(x.w, w3.y, acc[i].y);
            acc[i].z = fmaf(x.w, w3.z, acc[i].z); acc[i].w = fmaf(x.w, w3.w, acc[i].w);
        }
    }

    float4 bq = make_float4(0.f, 0.f, 0.f, 0.f);
    if (bias) bq = *(const float4*)(bias + loadc);
    float4 outv[4];
#pragma unroll
    for (int i = 0; i < 4; i++) {
        float4 v = acc[i];
        v.x += bq.x; v.y += bq.y; v.z += bq.z; v.w += bq.w;
        if (X2 == nullptr && relu == 0 && sums == nullptr) {} // keep structure simple
        outv[i] = v;
    }
#pragma unroll
    for (int i = 0; i < 4; i++) {
        if (relu) {
            outv[i].x = fmaxf(outv[i].x, 0.f); outv[i].y = fmaxf(outv[i].y, 0.f);
            outv[i].z = fmaxf(outv[i].z, 0.f); outv[i].w = fmaxf(outv[i].w, 0.f);
        }
    }
    if (c4 < 88) {
#pragma unroll
        for (int i = 0; i < 4; i++)
            *(float4*)(O + (size_t)(n0 + i) * ldo + cidx) = outv[i];
    }
    if (sums) {
        float s[4] = {0.f, 0.f, 0.f, 0.f}, s2[4] = {0.f, 0.f, 0.f, 0.f};
#pragma unroll
        for (int i = 0; i < 4; i++) {
            s[0] += outv[i].x; s2[0] += outv[i].x * outv[i].x;
            s[1] += outv[i].y; s2[1] += outv[i].y * outv[i].y;
            s[2] += outv[i].z; s2[2] += outv[i].z * outv[i].z;
            s[3] += outv[i].w; s2[3] += outv[i].w * outv[i].w;
        }
        int base = nq * 192 + cg * 8;
#pragma unroll
        for (int k = 0; k < 4; k++) { red[base + k] = s[k]; red[base + 4 + k] = s2[k]; }
        __syncthreads();
        if (t < 96) {
            int g = t >> 2, o = t & 3;
            float a = 0.f, b = 0.f;
#pragma unroll
            for (int q = 0; q < 8; q++) {
                a += red[q * 192 + g * 8 + o];
                b += red[q * 192 + g * 8 + 4 + o];
            }
            int c = 4 * g + o;
            if (c < 88) {
                atomicAdd(&sums[c], a);
                atomicAdd(&sums[C + c], b);
            }
        }
    }
}

// residual add variant: OUT = X@W + b + R (uses same core, R applied)
__global__ __launch_bounds__(192) void k_gemm3r(const float* __restrict__ X, int K,
                                                const float* __restrict__ W,
                                                const float* __restrict__ bias,
                                                const float* __restrict__ R,
                                                float* __restrict__ O,
                                                int ldw, int ldo,
                                                float* __restrict__ sums) {
    __shared__ float red[8 * 192];
    int t = threadIdx.x;
    int cg = t % 24, nq = t / 24;
    int c4 = 4 * cg;
    int cidx = c4;
    int loadc = cidx;
    if (loadc > ldw - 4) loadc = ldw - 4;
    int n0 = blockIdx.x * 32 + 4 * nq;
    const float* Xr = X + (size_t)n0 * K;

    float4 acc[4];
#pragma unroll
    for (int i = 0; i < 4; i++) acc[i] = make_float4(0.f, 0.f, 0.f, 0.f);

    for (int j = 0; j < K; j += 4) {
        const float* Wr = W + (size_t)j * ldw + loadc;
        float4 w0 = *(const float4*)(Wr);
        float4 w1 = *(const float4*)(Wr + ldw);
        float4 w2 = *(const float4*)(Wr + 2 * ldw);
        float4 w3 = *(const float4*)(Wr + 3 * ldw);
#pragma unroll
        for (int i = 0; i < 4; i++) {
            float4 x = *(const float4*)(Xr + (size_t)i * K + j);
            acc[i].x = fmaf(x.x, w0.x, acc[i].x); acc[i].y = fmaf(x.x, w0.y, acc[i].y);
            acc[i].z = fmaf(x.x, w0.z, acc[i].z); acc[i].w = fmaf(x.x, w0.w, acc[i].w);
            acc[i].x = fmaf(x.y, w1.x, acc[i].x); acc[i].y = fmaf(x.y, w1.y, acc[i].y);
            acc[i].z = fmaf(x.y, w1.z, acc[i].z); acc[i].w = fmaf(x.y, w1.w, acc[i].w);
            acc[i].x = fmaf(x.z, w2.x, acc[i].x); acc[i].y = fmaf(x.z, w2.y, acc[i].y);
            acc[i].z = fmaf(x.z, w2.z, acc[i].z); acc[i].w = fmaf(x.z, w2.w, acc[i].w);
            acc[i].x = fmaf(x.w, w3.x, acc[i].x); acc[i].y = fmaf(x.w, w3.y, acc[i].y);
            acc[i].z = fmaf(x.w, w3.z, acc[i].z); acc[i].w = fmaf(x.w, w3.w, acc[i].w);
        }
    }

    float4 bq = make_float4(0.f, 0.f, 0.f, 0.f);
    if (bias) bq = *(const float4*)(bias + loadc);
    float4 outv[4];
#pragma unroll
    for (int i = 0; i < 4; i++) {
        float4 v = acc[i];
        v.x += bq.x; v.y += bq.y; v.z += bq.z; v.w += bq.w;
        if (R && c4 < 88) {
            float4 rv = *(const float4*)(R + (size_t)(n0 + i) * ldo + cidx);
            v.x += rv.x; v.y += rv.y; v.z += rv.z; v.w += rv.w;
        }
        outv[i] = v;
    }
    if (c4 < 88) {
#pragma unroll
        for (int i = 0; i < 4; i++)
            *(float4*)(O + (size_t)(n0 + i) * ldo + cidx) = outv[i];
    }
    if (sums) {
        float s[4] = {0.f, 0.f, 0.f, 0.f}, s2[4] = {0.f, 0.f, 0.f, 0.f};
#pragma unroll
        for (int i = 0; i < 4; i++) {
            s[0] += outv[i].x; s2[0] += outv[i].x * outv[i].x;
            s[1] += outv[i].y; s2[1] += outv[i].y * outv[i].y;
            s[2] += outv[i].z; s2[2] += outv[i].z * outv[i].z;
            s[3] += outv[i].w; s2[3] += outv[i].w * outv[i].w;
        }
        int base = nq * 192 + cg * 8;
#pragma unroll
        for (int k = 0; k < 4; k++) { red[base + k] = s[k]; red[base + 4 + k] = s2[k]; }
        __syncthreads();
        if (t < 96) {
            int g = t >> 2, o = t & 3;
            float a = 0.f, b = 0.f;
#pragma unroll
            for (int q = 0; q < 8; q++) {
                a += red[q * 192 + g * 8 + o];
                b += red[q * 192 + g * 8 + 4 + o];
            }
            int c = 4 * g + o;
            if (c < 88) {
                atomicAdd(&sums[c], a);
                atomicAdd(&sums[C + c], b);
            }
        }
    }
}

// ---------------- flash attention: block per (graph, head, qtile) ----------
#define KCH 16
__global__ __launch_bounds__(128) void k_attn(const float* __restrict__ q,
                                              const float* __restrict__ kbuf,
                                              const float* __restrict__ vbuf,
                                              float* __restrict__ o) {
    int bx = blockIdx.x;
    int qt = bx & 3;
    int head = (bx >> 2) & 3;
    int g = bx >> 4;
    int t = threadIdx.x;
    int qnode = g * NPG + qt * 128 + t;
    const float* qr = q + (size_t)qnode * C + head * HD;
    float qreg[24], oreg[24];
#pragma unroll
    for (int d = 0; d < 24; d++) {
        qreg[d] = (d < HD) ? qr[d] * ATT_SCALE : 0.f;
        oreg[d] = 0.f;
    }
    float m = -1e30f, l = 0.f;
    __shared__ float Kt[64][24];
    __shared__ float Vt[64][24];
    for (int kt = 0; kt < NPG / 64; kt++) {
        __syncthreads();
        for (int idx = t; idx < 64 * HD; idx += 128) {
            int r = idx / HD, cc = idx % HD;
            int knode = g * NPG + kt * 64 + r;
            Kt[r][cc] = kbuf[(size_t)knode * C + head * HD + cc];
            Vt[r][cc] = vbuf[(size_t)knode * C + head * HD + cc];
        }
        for (int idx = t; idx < 64 * 2; idx += 128) {
            int r = idx >> 1, cc = HD + (idx & 1);
            Kt[r][cc] = 0.f; Vt[r][cc] = 0.f;
        }
        __syncthreads();
        for (int c0 = 0; c0 < 64; c0 += KCH) {
            float sc[KCH];
#pragma unroll
            for (int i = 0; i < KCH; i++) {
                float s = 0.f;
#pragma unroll
                for (int d = 0; d < 24; d++) s += qreg[d] * Kt[c0 + i][d];
                sc[i] = s;
            }
            float tmax = sc[0];
#pragma unroll
            for (int i = 1; i < KCH; i++) tmax = fmaxf(tmax, sc[i]);
            float newm = fmaxf(m, tmax);
            float alpha = __expf(m - newm);
            l *= alpha;
#pragma unroll
            for (int d = 0; d < 24; d++) oreg[d] *= alpha;
            m = newm;
#pragma unroll
            for (int i = 0; i < KCH; i++) {
                float p = __expf(sc[i] - m);
                l += p;
#pragma unroll
                for (int d = 0; d < 24; d++) oreg[d] += p * Vt[c0 + i][d];
            }
        }
    }
    float inv = 1.f / l;
    float* orow = o + (size_t)qnode * C + head * HD;
#pragma unroll
    for (int d = 0; d < HD; d++) orow[d] = oreg[d] * inv;
}

// ---------------- out3 = bn1(s1) + bn2(s2), stats from raw sums ------------
__global__ void k_out3(const float* __restrict__ s1, const float* __restrict__ s2,
                       const float* __restrict__ st1, const float* __restrict__ st2,
                       const float* __restrict__ g1, const float* __restrict__ b1,
                       const float* __restrict__ g2, const float* __restrict__ b2,
                       float* __restrict__ out3) {
    int gid = blockIdx.x * blockDim.x + threadIdx.x;
    if (gid >= N_NODES * C) return;
    int c = gid % C;
    float mu1 = st1[c] * INV_N;
    float r1 = rsqrtf(st1[C + c] * INV_N - mu1 * mu1 + BN_EPS);
    float mu2 = st2[c] * INV_N;
    float r2 = rsqrtf(st2[C + c] * INV_N - mu2 * mu2 + BN_EPS);
    float a = (s1[gid] - mu1) * r1 * g1[c] + b1[c];
    float b = (s2[gid] - mu2) * r2 * g2[c] + b2[c];
    out3[gid] = a + b;
}

// ---------------- h = bn3(s3), stats from raw sums -------------------------
__global__ void k_bn_apply(const float* __restrict__ s, const float* __restrict__ st,
                           const float* __restrict__ g, const float* __restrict__ b,
                           float* __restrict__ h) {
    int gid = blockIdx.x * blockDim.x + threadIdx.x;
    if (gid >= N_NODES * C) return;
    int c = gid % C;
    float mu = st[c] * INV_N;
    float r = rsqrtf(st[C + c] * INV_N - mu * mu + BN_EPS);
    h[gid] = (s[gid] - mu) * r * g[c] + b[c];
}

// ---------------- final: logit = relu(P[se]+Q[de]+Eemb@W1_emb) . w2 + b2 ---
__global__ void k_final2(const float* __restrict__ P, const float* __restrict__ Q,
                         const int* __restrict__ ei, const float* __restrict__ Eemb,
                         const float* __restrict__ w1emb, const float* __restrict__ w2,
                         const float* __restrict__ b2, float* __restrict__ out) {
    int wid = (blockIdx.x * blockDim.x + threadIdx.x) >> 6;
    int lane = threadIdx.x & 63;
    if (wid >= EE) return;
    int se = ei[wid], de = ei[EE + wid];
    const float* ps = P + (size_t)se * C;
    const float* qd = Q + (size_t)de * C;
    const float* em = Eemb + (size_t)wid * EEMB;
    float e0 = em[0], e1 = em[1], e2 = em[2], e3 = em[3];
    float e4 = em[4], e5 = em[5], e6 = em[6], e7 = em[7];
    int c1 = lane, c2 = lane + 64;
    bool has2 = (c2 < C);
    float a1 = ps[c1] + qd[c1];
    float a2 = has2 ? (ps[c2] + qd[c2]) : 0.f;
    a1 += e0 * w1emb[0 * C + c1] + e1 * w1emb[1 * C + c1] + e2 * w1emb[2 * C + c1] +
          e3 * w1emb[3 * C + c1] + e4 * w1emb[4 * C + c1] + e5 * w1emb[5 * C + c1] +
          e6 * w1emb[6 * C + c1] + e7 * w1emb[7 * C + c1];
    if (has2)
        a2 += e0 * w1emb[0 * C + c2] + e1 * w1emb[1 * C + c2] + e2 * w1emb[2 * C + c2] +
              e3 * w1emb[3 * C + c2] + e4 * w1emb[4 * C + c2] + e5 * w1emb[5 * C + c2] +
              e6 * w1emb[6 * C + c2] + e7 * w1emb[7 * C + c2];
    a1 = fmaxf(a1, 0.f);
    a2 = fmaxf(a2, 0.f);
    float part = a1 * w2[c1] + (has2 ? a2 * w2[c2] : 0.f);
#pragma unroll
    for (int off = 32; off > 0; off >>= 1) part += __shfl_xor(part, off, 64);
    if (lane == 0) out[wid] = part + b2[0];
}

// ===========================================================================
extern "C" void kernel_launch(void* const* d_in, const int* in_sizes, int n_in,
                              void* d_out, int out_size, void* d_ws, size_t ws_size,
                              hipStream_t stream) {
    const float* xd = (const float*)d_in[0];
    const int* A_ei = (const int*)d_in[1];
    const float* Aattr = (const float*)d_in[2];
    const int* E_ei = (const int*)d_in[3];
    const float* Eattr = (const float*)d_in[4];
    const float* AW = (const float*)d_in[6];
    const float* pe_g = (const float*)d_in[7];
    const float* pe_bt = (const float*)d_in[8];
    const float* pe_w = (const float*)d_in[9];
    const float* pe_b = (const float*)d_in[10];
    const float* gine_ew = (const float*)d_in[11];
    const float* gine_eb = (const float*)d_in[12];
    const float* gine_w1 = (const float*)d_in[13];
    const float* gine_b1 = (const float*)d_in[14];
    const float* gine_w2 = (const float*)d_in[15];
    const float* gine_b2 = (const float*)d_in[16];
    const float* wq = (const float*)d_in[17];
    const float* wk = (const float*)d_in[18];
    const float* wv = (const float*)d_in[19];
    const float* wo = (const float*)d_in[20];
    const float* bq = (const float*)d_in[21];
    const float* bk = (const float*)d_in[22];
    const float* bv = (const float*)d_in[23];
    const float* bo = (const float*)d_in[24];
    const float* n1g = (const float*)d_in[25];
    const float* n2g = (const float*)d_in[26];
    const float* n3g = (const float*)d_in[27];
    const float* n1b = (const float*)d_in[28];
    const float* n2b = (const float*)d_in[29];
    const float* n3b = (const float*)d_in[30];
    const float* mw1 = (const float*)d_in[31];
    const float* mb1 = (const float*)d_in[32];
    const float* mw2 = (const float*)d_in[33];
    const float* mb2 = (const float*)d_in[34];
    const float* ew1 = (const float*)d_in[35];
    const float* eb1 = (const float*)d_in[36];
    const float* ew2 = (const float*)d_in[37];
    const float* eb2 = (const float*)d_in[38];

    float* ws = (float*)d_ws;
    size_t off = 0;
    auto alloc = [&](size_t n) { float* p = ws + off; off += n; return p; };
    float* Aemb = alloc((size_t)EA * EEMB);
    float* Eemb = alloc((size_t)EE * EEMB);
    float* h = alloc((size_t)N_NODES * C);
    float* aggr = alloc((size_t)N_NODES * C);
    float* u = alloc((size_t)N_NODES * C);
    float* s1 = alloc((size_t)N_NODES * C);
    float* qb = alloc((size_t)N_NODES * C);
    float* kb = alloc((size_t)N_NODES * C);
    float* vb = alloc((size_t)N_NODES * C);
    float* ob = alloc((size_t)N_NODES * C);
    float* s2 = alloc((size_t)N_NODES * C);
    float* out3 = alloc((size_t)N_NODES * C);
    float* u2 = alloc((size_t)N_NODES * 176);
    float* stats = alloc(2048);
    float* st1 = stats;
    float* st2 = stats + 176;
    float* st3 = stats + 352;
    float* pe_mean = stats + 576;
    float* pe_rstd = stats + 608;

    const int NT = 256;
    const int nc_blocks = (N_NODES * C + NT - 1) / NT;
    const dim3 gA(512, 1, 1), gQKV(512, 1, 3), gU2(512, 2, 1);

    // --- prologue ---
    // (EA+EE) = 393216 edges = 1536 blocks x 256 threads, one thread per edge
    k_edge_emb4<<<1536, 256, 0, stream>>>(Aattr, Eattr, AW, Aemb, Eemb);
    k_colstats<<<PE_RAW, NT, 0, stream>>>(xd + XF, XD, N_NODES, pe_mean, pe_rstd);
    k_build_h<<<nc_blocks, NT, 0, stream>>>(xd, pe_mean, pe_rstd, pe_g, pe_bt, pe_w, pe_b, h);

    // --- layers ---
    for (int l = 0; l < NL; l++) {
        const float* ew = gine_ew + (size_t)l * EEMB * C;
        const float* eb = gine_eb + (size_t)l * C;
        const float* w1 = gine_w1 + (size_t)l * C * C;
        const float* b1 = gine_b1 + (size_t)l * C;
        const float* w2 = gine_w2 + (size_t)l * C * C;
        const float* b2 = gine_b2 + (size_t)l * C;
        const float* lwq = wq + (size_t)l * C * C;
        const float* lwk = wk + (size_t)l * C * C;
        const float* lwv = wv + (size_t)l * C * C;
        const float* lwo = wo + (size_t)l * C * C;
        const float* lbq = bq + (size_t)l * C;
        const float* lbk = bk + (size_t)l * C;
        const float* lbv = bv + (size_t)l * C;
        const float* lbo = bo + (size_t)l * C;
        const float* l1g = n1g + (size_t)l * C;
        const float* l1b = n1b + (size_t)l * C;
        const float* l2g = n2g + (size_t)l * C;
        const float* l2b = n2b + (size_t)l * C;
        const float* l3g = n3g + (size_t)l * C;
        const float* l3b = n3b + (size_t)l * C;
        const float* lmw1 = mw1 + (size_t)l * C * 176;
        const float* lmb1 = mb1 + (size_t)l * 176;
        const float* lmw2 = mw2 + (size_t)l * 176 * C;
        const float* lmb2 = mb2 + (size_t)l * C;

        hipMemsetAsync(aggr, 0, (size_t)N_NODES * C * sizeof(float), stream);
        hipMemsetAsync(stats, 0, 528 * sizeof(float), stream);
        k_gine_edge2<<<(EA * 22) / 256, 256, 0, stream>>>(Aemb, A_ei, h, ew, eb, aggr);
        // u = relu((h+aggr)@w1 + b1)
        k_gemm3<<<gA, 192, 0, stream>>>(h, aggr, C, w1, w1, w1, b1, b1, b1,
                                        u, u, u, C, C, 1, nullptr);
        // s1 = u@w2 + b2 + h  (+stats1)
        k_gemm3r<<<gA, 192, 0, stream>>>(u, C, w2, b2, h, s1, C, C, st1);
        // q,k,v fused via z
        k_gemm3<<<gQKV, 192, 0, stream>>>(h, nullptr, C, lwq, lwk, lwv, lbq, lbk, lbv,
                                          qb, kb, vb, C, C, 0, nullptr);
        k_attn<<<N_GRAPHS * NH * 4, 128, 0, stream>>>(qb, kb, vb, ob);
        // s2 = o@wo + bo + h  (+stats2)
        k_gemm3r<<<gA, 192, 0, stream>>>(ob, C, lwo, lbo, h, s2, C, C, st2);
        k_out3<<<nc_blocks, NT, 0, stream>>>(s1, s2, st1, st2, l1g, l1b, l2g, l2b, out3);
        // u2 = relu(out3@mw1 + mb1)   (176 cols -> y=2)
        k_gemm3<<<gU2, 192, 0, stream>>>(out3, nullptr, C, lmw1, lmw1, lmw1,
                                         lmb1, lmb1, lmb1, u2, u2, u2, 176, 176, 1, nullptr);
        // s3 = u2@mw2 + mb2 + out3  (+stats3)
        k_gemm3r<<<gA, 192, 0, stream>>>(u2, 176, lmw2, lmb2, out3, s1, C, C, st3);
        k_bn_apply<<<nc_blocks, NT, 0, stream>>>(s1, st3, l3g, l3b, h);
    }

    // --- epilogue: factored edge MLP ---
    k_gemm3r<<<gA, 192, 0, stream>>>(h, C, ew1, eb1, nullptr, qb, C, C, nullptr);                 // P
    k_gemm3r<<<gA, 192, 0, stream>>>(h, C, ew1 + (size_t)C * C, nullptr, nullptr, kb, C, C, nullptr); // Q
    k_final2<<<(EE * 64 + NT - 1) / NT, NT, 0, stream>>>(qb, kb, E_ei, Eemb,
                                                         ew1 + (size_t)2 * C * C, ew2, eb2,
                                                         (float*)d_out);
}

// Round 2
// 4036.469 us; speedup vs baseline: 1.1294x; 1.1294x over previous
//
#include <hip/hip_runtime.h>

#define N_NODES 16384
#define N_GRAPHS 32
#define NPG 512
#define C 88
#define NL 6
#define NH 4
#define HD 22
#define EA 131072
#define EE 262144
#define EDIM 197
#define EEMB 8
#define PE_RAW 18
#define PE_DIM 10
#define XD 96
#define XF 78
#define BN_EPS 1e-5f
#define ATT_SCALE 0.21320071635561044f
#define INV_N (1.0f / 16384.0f)

// ---------------- edge attr embedding v5: 8 lanes/edge, j-split ------------
// lane = (edge_in_octet, j). Each lane computes ONE output j for its edge
// over all k -> no cross-lane reduction at all.
// attr: 8 j-lanes of an edge read the SAME float4 (merged); wave covers 8
//   rows' contiguous bytes sequentially -> within-wave line reuse, no L1
//   thrash (the v4 failure mode: per-lane 788B-stride reads x 20 waves/CU).
// W: transposed [8][204] in LDS (pad 204: 16B-aligned rows, bank-quad starts
//   12j mod 32 all distinct -> conflict-free ds_read_b128; same-j lanes
//   broadcast).
__global__ __launch_bounds__(256) void k_edge_emb5(const float* __restrict__ Aattr,
                                                   const float* __restrict__ Eattr,
                                                   const float* __restrict__ W,
                                                   float* __restrict__ Aemb,
                                                   float* __restrict__ Eemb) {
    __shared__ float Wt[8 * 204];
    int t = threadIdx.x;
    for (int idx = t; idx < EDIM * EEMB; idx += 256) {
        int k = idx >> 3, j = idx & 7;
        Wt[j * 204 + k] = W[idx];
    }
    __syncthreads();
    int wib = t >> 6, lane = t & 63;
    int e_loc = lane >> 3, j = lane & 7;
    const float* wrow = Wt + j * 204;
    // wave owns 64 consecutive edges; EA = 2048*64 -> A/E uniform per wave
    long wbase = ((long)blockIdx.x * 4 + wib) * 64;
    for (int oct = 0; oct < 8; oct++) {
        long e = wbase + oct * 8 + e_loc;
        const float* attr;
        float* dst;
        if (e < EA) {
            attr = Aattr + e * EDIM;
            dst = Aemb + e * EEMB;
        } else {
            long q = e - EA;
            attr = Eattr + q * EDIM;
            dst = Eemb + q * EEMB;
        }
        float acc0 = 0.f, acc1 = 0.f;
#pragma unroll 7
        for (int i = 0; i < 49; i++) {
            float4 a = *(const float4*)(attr + 4 * i);      // same addr across 8 j-lanes
            float4 w = *(const float4*)(wrow + 4 * i);      // aligned ds_read_b128
            acc0 = fmaf(a.x, w.x, acc0);
            acc1 = fmaf(a.y, w.y, acc1);
            acc0 = fmaf(a.z, w.z, acc0);
            acc1 = fmaf(a.w, w.w, acc1);
        }
        acc0 += acc1;
        acc0 = fmaf(attr[196], wrow[196], acc0);            // tail k=196
        dst[j] = acc0;                                      // 64 consecutive floats/octet
    }
}

// ---------------- per-column mean/rstd (only for the small PE BN) ----------
__global__ void k_colstats(const float* __restrict__ X, int ldx, int nrows,
                           float* __restrict__ mean, float* __restrict__ rstd) {
    int c = blockIdx.x;
    int t = threadIdx.x;
    float s = 0.f, s2 = 0.f;
    for (int r = t; r < nrows; r += 256) {
        float v = X[(size_t)r * ldx + c];
        s += v; s2 += v * v;
    }
    __shared__ float ls[256], ls2[256];
    ls[t] = s; ls2[t] = s2;
    __syncthreads();
    for (int off = 128; off > 0; off >>= 1) {
        if (t < off) { ls[t] += ls[t + off]; ls2[t] += ls2[t + off]; }
        __syncthreads();
    }
    if (t == 0) {
        float m = ls[0] / nrows;
        float var = ls2[0] / nrows - m * m;
        mean[c] = m;
        rstd[c] = rsqrtf(var + BN_EPS);
    }
}

// ---------------- build h0 = [x, bn(pe)@pe_w + pe_b] -----------------------
__global__ void k_build_h(const float* __restrict__ xd, const float* __restrict__ pe_mean,
                          const float* __restrict__ pe_rstd, const float* __restrict__ pe_g,
                          const float* __restrict__ pe_bt, const float* __restrict__ pe_w,
                          const float* __restrict__ pe_b, float* __restrict__ h) {
    int gid = blockIdx.x * blockDim.x + threadIdx.x;
    if (gid >= N_NODES * C) return;
    int n = gid / C, c = gid % C;
    float v;
    if (c < XF) {
        v = xd[(size_t)n * XD + c];
    } else {
        int j = c - XF;
        float acc = pe_b[j];
#pragma unroll
        for (int i = 0; i < PE_RAW; i++) {
            float pn = (xd[(size_t)n * XD + XF + i] - pe_mean[i]) * pe_rstd[i] * pe_g[i] + pe_bt[i];
            acc += pn * pe_w[i * PE_DIM + j];
        }
        v = acc;
    }
    h[gid] = v;
}

// ---------------- GINE edge message + scatter-add (quad version) -----------
__global__ void k_gine_edge2(const float* __restrict__ Aemb, const int* __restrict__ ei,
                             const float* __restrict__ h, const float* __restrict__ ew,
                             const float* __restrict__ eb, float* __restrict__ aggr) {
    int gid = blockIdx.x * blockDim.x + threadIdx.x;   // e*22 + q
    int e = gid / 22, q = gid % 22;
    const float* emb = Aemb + (size_t)e * EEMB;
    float4 acc = *(const float4*)(eb + 4 * q);
#pragma unroll
    for (int j = 0; j < EEMB; j++) {
        float ej = emb[j];
        float4 w = *(const float4*)(ew + j * C + 4 * q);
        acc.x = fmaf(ej, w.x, acc.x); acc.y = fmaf(ej, w.y, acc.y);
        acc.z = fmaf(ej, w.z, acc.z); acc.w = fmaf(ej, w.w, acc.w);
    }
    int s = ei[e], d = ei[EA + e];
    float4 hv = *(const float4*)(h + (size_t)s * C + 4 * q);
    float* ab = aggr + (size_t)d * C + 4 * q;
    float m0 = fmaxf(acc.x + hv.x, 0.f), m1 = fmaxf(acc.y + hv.y, 0.f);
    float m2 = fmaxf(acc.z + hv.z, 0.f), m3 = fmaxf(acc.w + hv.w, 0.f);
    atomicAdd(ab + 0, m0); atomicAdd(ab + 1, m1);
    atomicAdd(ab + 2, m2); atomicAdd(ab + 3, m3);
}

// ---------------- register-tiled GEMM, no LDS staging ----------------------
// tile: 32 nodes x 88 cols per block; thread = 4 nodes x 4 cols.
// block 192 = 24 col-groups x 8 node-groups (2 col-groups are padding).
// W read b128 from L1 (broadcast across node-groups); X read b128 along K
// (broadcast across col-groups). Optional: X2 added to X, residual R, relu,
// and fused BN raw-moment accumulation into sums[0:88]=sum, sums[88:176]=sumsq.
// z-dim selects (W,b,O) triple for fused q/k/v.
__global__ __launch_bounds__(192) void k_gemm3(const float* __restrict__ X,
                                               const float* __restrict__ X2, int K,
                                               const float* __restrict__ Wa,
                                               const float* __restrict__ Wb,
                                               const float* __restrict__ Wc,
                                               const float* __restrict__ ba,
                                               const float* __restrict__ bb,
                                               const float* __restrict__ bc,
                                               float* __restrict__ Oa,
                                               float* __restrict__ Ob,
                                               float* __restrict__ Oc,
                                               int ldw, int ldo, int relu,
                                               float* __restrict__ sums) {
    __shared__ float red[8 * 192];
    int t = threadIdx.x;
    int z = blockIdx.z;
    const float* W = (z == 0) ? Wa : (z == 1) ? Wb : Wc;
    const float* bias = (z == 0) ? ba : (z == 1) ? bb : bc;
    float* O = (z == 0) ? Oa : (z == 1) ? Ob : Oc;

    int cg = t % 24, nq = t / 24;
    int c4 = 4 * cg;
    int c_off = 88 * blockIdx.y;
    int cidx = c_off + c4;
    int loadc = cidx;
    if (loadc > ldw - 4) loadc = ldw - 4;
    int n0 = blockIdx.x * 32 + 4 * nq;
    const float* Xr = X + (size_t)n0 * K;
    const float* X2r = X2 ? X2 + (size_t)n0 * K : nullptr;

    float4 acc[4];
#pragma unroll
    for (int i = 0; i < 4; i++) acc[i] = make_float4(0.f, 0.f, 0.f, 0.f);

    for (int j = 0; j < K; j += 4) {
        const float* Wr = W + (size_t)j * ldw + loadc;
        float4 w0 = *(const float4*)(Wr);
        float4 w1 = *(const float4*)(Wr + ldw);
        float4 w2 = *(const float4*)(Wr + 2 * ldw);
        float4 w3 = *(const float4*)(Wr + 3 * ldw);
#pragma unroll
        for (int i = 0; i < 4; i++) {
            float4 x = *(const float4*)(Xr + (size_t)i * K + j);
            if (X2r) {
                float4 x2 = *(const float4*)(X2r + (size_t)i * K + j);
                x.x += x2.x; x.y += x2.y; x.z += x2.z; x.w += x2.w;
            }
            acc[i].x = fmaf(x.x, w0.x, acc[i].x); acc[i].y = fmaf(x.x, w0.y, acc[i].y);
            acc[i].z = fmaf(x.x, w0.z, acc[i].z); acc[i].w = fmaf(x.x, w0.w, acc[i].w);
            acc[i].x = fmaf(x.y, w1.x, acc[i].x); acc[i].y = fmaf(x.y, w1.y, acc[i].y);
            acc[i].z = fmaf(x.y, w1.z, acc[i].z); acc[i].w = fmaf(x.y, w1.w, acc[i].w);
            acc[i].x = fmaf(x.z, w2.x, acc[i].x); acc[i].y = fmaf(x.z, w2.y, acc[i].y);
            acc[i].z = fmaf(x.z, w2.z, acc[i].z); acc[i].w = fmaf(x.z, w2.w, acc[i].w);
            acc[i].x = fmaf(x.w, w3.x, acc[i].x); acc[i].y = fmaf(x.w, w3.y, acc[i].y);
            acc[i].z = fmaf(x.w, w3.z, acc[i].z); acc[i].w = fmaf(x.w, w3.w, acc[i].w);
        }
    }

    float4 bq = make_float4(0.f, 0.f, 0.f, 0.f);
    if (bias) bq = *(const float4*)(bias + loadc);
    float4 outv[4];
#pragma unroll
    for (int i = 0; i < 4; i++) {
        float4 v = acc[i];
        v.x += bq.x; v.y += bq.y; v.z += bq.z; v.w += bq.w;
        outv[i] = v;
    }
#pragma unroll
    for (int i = 0; i < 4; i++) {
        if (relu) {
            outv[i].x = fmaxf(outv[i].x, 0.f); outv[i].y = fmaxf(outv[i].y, 0.f);
            outv[i].z = fmaxf(outv[i].z, 0.f); outv[i].w = fmaxf(outv[i].w, 0.f);
        }
    }
    if (c4 < 88) {
#pragma unroll
        for (int i = 0; i < 4; i++)
            *(float4*)(O + (size_t)(n0 + i) * ldo + cidx) = outv[i];
    }
    if (sums) {
        float s[4] = {0.f, 0.f, 0.f, 0.f}, s2[4] = {0.f, 0.f, 0.f, 0.f};
#pragma unroll
        for (int i = 0; i < 4; i++) {
            s[0] += outv[i].x; s2[0] += outv[i].x * outv[i].x;
            s[1] += outv[i].y; s2[1] += outv[i].y * outv[i].y;
            s[2] += outv[i].z; s2[2] += outv[i].z * outv[i].z;
            s[3] += outv[i].w; s2[3] += outv[i].w * outv[i].w;
        }
        int base = nq * 192 + cg * 8;
#pragma unroll
        for (int k = 0; k < 4; k++) { red[base + k] = s[k]; red[base + 4 + k] = s2[k]; }
        __syncthreads();
        if (t < 96) {
            int g = t >> 2, o = t & 3;
            float a = 0.f, b = 0.f;
#pragma unroll
            for (int q = 0; q < 8; q++) {
                a += red[q * 192 + g * 8 + o];
                b += red[q * 192 + g * 8 + 4 + o];
            }
            int c = 4 * g + o;
            if (c < 88) {
                atomicAdd(&sums[c], a);
                atomicAdd(&sums[C + c], b);
            }
        }
    }
}

// residual add variant: OUT = X@W + b + R (uses same core, R applied)
__global__ __launch_bounds__(192) void k_gemm3r(const float* __restrict__ X, int K,
                                                const float* __restrict__ W,
                                                const float* __restrict__ bias,
                                                const float* __restrict__ R,
                                                float* __restrict__ O,
                                                int ldw, int ldo,
                                                float* __restrict__ sums) {
    __shared__ float red[8 * 192];
    int t = threadIdx.x;
    int cg = t % 24, nq = t / 24;
    int c4 = 4 * cg;
    int cidx = c4;
    int loadc = cidx;
    if (loadc > ldw - 4) loadc = ldw - 4;
    int n0 = blockIdx.x * 32 + 4 * nq;
    const float* Xr = X + (size_t)n0 * K;

    float4 acc[4];
#pragma unroll
    for (int i = 0; i < 4; i++) acc[i] = make_float4(0.f, 0.f, 0.f, 0.f);

    for (int j = 0; j < K; j += 4) {
        const float* Wr = W + (size_t)j * ldw + loadc;
        float4 w0 = *(const float4*)(Wr);
        float4 w1 = *(const float4*)(Wr + ldw);
        float4 w2 = *(const float4*)(Wr + 2 * ldw);
        float4 w3 = *(const float4*)(Wr + 3 * ldw);
#pragma unroll
        for (int i = 0; i < 4; i++) {
            float4 x = *(const float4*)(Xr + (size_t)i * K + j);
            acc[i].x = fmaf(x.x, w0.x, acc[i].x); acc[i].y = fmaf(x.x, w0.y, acc[i].y);
            acc[i].z = fmaf(x.x, w0.z, acc[i].z); acc[i].w = fmaf(x.x, w0.w, acc[i].w);
            acc[i].x = fmaf(x.y, w1.x, acc[i].x); acc[i].y = fmaf(x.y, w1.y, acc[i].y);
            acc[i].z = fmaf(x.y, w1.z, acc[i].z); acc[i].w = fmaf(x.y, w1.w, acc[i].w);
            acc[i].x = fmaf(x.z, w2.x, acc[i].x); acc[i].y = fmaf(x.z, w2.y, acc[i].y);
            acc[i].z = fmaf(x.z, w2.z, acc[i].z); acc[i].w = fmaf(x.z, w2.w, acc[i].w);
            acc[i].x = fmaf(x.w, w3.x, acc[i].x); acc[i].y = fmaf(x.w, w3.y, acc[i].y);
            acc[i].z = fmaf(x.w, w3.z, acc[i].z); acc[i].w = fmaf(x.w, w3.w, acc[i].w);
        }
    }

    float4 bq = make_float4(0.f, 0.f, 0.f, 0.f);
    if (bias) bq = *(const float4*)(bias + loadc);
    float4 outv[4];
#pragma unroll
    for (int i = 0; i < 4; i++) {
        float4 v = acc[i];
        v.x += bq.x; v.y += bq.y; v.z += bq.z; v.w += bq.w;
        if (R && c4 < 88) {
            float4 rv = *(const float4*)(R + (size_t)(n0 + i) * ldo + cidx);
            v.x += rv.x; v.y += rv.y; v.z += rv.z; v.w += rv.w;
        }
        outv[i] = v;
    }
    if (c4 < 88) {
#pragma unroll
        for (int i = 0; i < 4; i++)
            *(float4*)(O + (size_t)(n0 + i) * ldo + cidx) = outv[i];
    }
    if (sums) {
        float s[4] = {0.f, 0.f, 0.f, 0.f}, s2[4] = {0.f, 0.f, 0.f, 0.f};
#pragma unroll
        for (int i = 0; i < 4; i++) {
            s[0] += outv[i].x; s2[0] += outv[i].x * outv[i].x;
            s[1] += outv[i].y; s2[1] += outv[i].y * outv[i].y;
            s[2] += outv[i].z; s2[2] += outv[i].z * outv[i].z;
            s[3] += outv[i].w; s2[3] += outv[i].w * outv[i].w;
        }
        int base = nq * 192 + cg * 8;
#pragma unroll
        for (int k = 0; k < 4; k++) { red[base + k] = s[k]; red[base + 4 + k] = s2[k]; }
        __syncthreads();
        if (t < 96) {
            int g = t >> 2, o = t & 3;
            float a = 0.f, b = 0.f;
#pragma unroll
            for (int q = 0; q < 8; q++) {
                a += red[q * 192 + g * 8 + o];
                b += red[q * 192 + g * 8 + 4 + o];
            }
            int c = 4 * g + o;
            if (c < 88) {
                atomicAdd(&sums[c], a);
                atomicAdd(&sums[C + c], b);
            }
        }
    }
}

// ---------------- flash attention: block per (graph, head, qtile) ----------
#define KCH 16
__global__ __launch_bounds__(128) void k_attn(const float* __restrict__ q,
                                              const float* __restrict__ kbuf,
                                              const float* __restrict__ vbuf,
                                              float* __restrict__ o) {
    int bx = blockIdx.x;
    int qt = bx & 3;
    int head = (bx >> 2) & 3;
    int g = bx >> 4;
    int t = threadIdx.x;
    int qnode = g * NPG + qt * 128 + t;
    const float* qr = q + (size_t)qnode * C + head * HD;
    float qreg[24], oreg[24];
#pragma unroll
    for (int d = 0; d < 24; d++) {
        qreg[d] = (d < HD) ? qr[d] * ATT_SCALE : 0.f;
        oreg[d] = 0.f;
    }
    float m = -1e30f, l = 0.f;
    __shared__ float Kt[64][24];
    __shared__ float Vt[64][24];
    for (int kt = 0; kt < NPG / 64; kt++) {
        __syncthreads();
        for (int idx = t; idx < 64 * HD; idx += 128) {
            int r = idx / HD, cc = idx % HD;
            int knode = g * NPG + kt * 64 + r;
            Kt[r][cc] = kbuf[(size_t)knode * C + head * HD + cc];
            Vt[r][cc] = vbuf[(size_t)knode * C + head * HD + cc];
        }
        for (int idx = t; idx < 64 * 2; idx += 128) {
            int r = idx >> 1, cc = HD + (idx & 1);
            Kt[r][cc] = 0.f; Vt[r][cc] = 0.f;
        }
        __syncthreads();
        for (int c0 = 0; c0 < 64; c0 += KCH) {
            float sc[KCH];
#pragma unroll
            for (int i = 0; i < KCH; i++) {
                float s = 0.f;
#pragma unroll
                for (int d = 0; d < 24; d++) s += qreg[d] * Kt[c0 + i][d];
                sc[i] = s;
            }
            float tmax = sc[0];
#pragma unroll
            for (int i = 1; i < KCH; i++) tmax = fmaxf(tmax, sc[i]);
            float newm = fmaxf(m, tmax);
            float alpha = __expf(m - newm);
            l *= alpha;
#pragma unroll
            for (int d = 0; d < 24; d++) oreg[d] *= alpha;
            m = newm;
#pragma unroll
            for (int i = 0; i < KCH; i++) {
                float p = __expf(sc[i] - m);
                l += p;
#pragma unroll
                for (int d = 0; d < 24; d++) oreg[d] += p * Vt[c0 + i][d];
            }
        }
    }
    float inv = 1.f / l;
    float* orow = o + (size_t)qnode * C + head * HD;
#pragma unroll
    for (int d = 0; d < HD; d++) orow[d] = oreg[d] * inv;
}

// ---------------- out3 = bn1(s1) + bn2(s2), stats from raw sums ------------
__global__ void k_out3(const float* __restrict__ s1, const float* __restrict__ s2,
                       const float* __restrict__ st1, const float* __restrict__ st2,
                       const float* __restrict__ g1, const float* __restrict__ b1,
                       const float* __restrict__ g2, const float* __restrict__ b2,
                       float* __restrict__ out3) {
    int gid = blockIdx.x * blockDim.x + threadIdx.x;
    if (gid >= N_NODES * C) return;
    int c = gid % C;
    float mu1 = st1[c] * INV_N;
    float r1 = rsqrtf(st1[C + c] * INV_N - mu1 * mu1 + BN_EPS);
    float mu2 = st2[c] * INV_N;
    float r2 = rsqrtf(st2[C + c] * INV_N - mu2 * mu2 + BN_EPS);
    float a = (s1[gid] - mu1) * r1 * g1[c] + b1[c];
    float b = (s2[gid] - mu2) * r2 * g2[c] + b2[c];
    out3[gid] = a + b;
}

// ---------------- h = bn3(s3), stats from raw sums -------------------------
__global__ void k_bn_apply(const float* __restrict__ s, const float* __restrict__ st,
                           const float* __restrict__ g, const float* __restrict__ b,
                           float* __restrict__ h) {
    int gid = blockIdx.x * blockDim.x + threadIdx.x;
    if (gid >= N_NODES * C) return;
    int c = gid % C;
    float mu = st[c] * INV_N;
    float r = rsqrtf(st[C + c] * INV_N - mu * mu + BN_EPS);
    h[gid] = (s[gid] - mu) * r * g[c] + b[c];
}

// ---------------- final: logit = relu(P[se]+Q[de]+Eemb@W1_emb) . w2 + b2 ---
__global__ void k_final2(const float* __restrict__ P, const float* __restrict__ Q,
                         const int* __restrict__ ei, const float* __restrict__ Eemb,
                         const float* __restrict__ w1emb, const float* __restrict__ w2,
                         const float* __restrict__ b2, float* __restrict__ out) {
    int wid = (blockIdx.x * blockDim.x + threadIdx.x) >> 6;
    int lane = threadIdx.x & 63;
    if (wid >= EE) return;
    int se = ei[wid], de = ei[EE + wid];
    const float* ps = P + (size_t)se * C;
    const float* qd = Q + (size_t)de * C;
    const float* em = Eemb + (size_t)wid * EEMB;
    float e0 = em[0], e1 = em[1], e2 = em[2], e3 = em[3];
    float e4 = em[4], e5 = em[5], e6 = em[6], e7 = em[7];
    int c1 = lane, c2 = lane + 64;
    bool has2 = (c2 < C);
    float a1 = ps[c1] + qd[c1];
    float a2 = has2 ? (ps[c2] + qd[c2]) : 0.f;
    a1 += e0 * w1emb[0 * C + c1] + e1 * w1emb[1 * C + c1] + e2 * w1emb[2 * C + c1] +
          e3 * w1emb[3 * C + c1] + e4 * w1emb[4 * C + c1] + e5 * w1emb[5 * C + c1] +
          e6 * w1emb[6 * C + c1] + e7 * w1emb[7 * C + c1];
    if (has2)
        a2 += e0 * w1emb[0 * C + c2] + e1 * w1emb[1 * C + c2] + e2 * w1emb[2 * C + c2] +
              e3 * w1emb[3 * C + c2] + e4 * w1emb[4 * C + c2] + e5 * w1emb[5 * C + c2] +
              e6 * w1emb[6 * C + c2] + e7 * w1emb[7 * C + c2];
    a1 = fmaxf(a1, 0.f);
    a2 = fmaxf(a2, 0.f);
    float part = a1 * w2[c1] + (has2 ? a2 * w2[c2] : 0.f);
#pragma unroll
    for (int off = 32; off > 0; off >>= 1) part += __shfl_xor(part, off, 64);
    if (lane == 0) out[wid] = part + b2[0];
}

// ===========================================================================
extern "C" void kernel_launch(void* const* d_in, const int* in_sizes, int n_in,
                              void* d_out, int out_size, void* d_ws, size_t ws_size,
                              hipStream_t stream) {
    const float* xd = (const float*)d_in[0];
    const int* A_ei = (const int*)d_in[1];
    const float* Aattr = (const float*)d_in[2];
    const int* E_ei = (const int*)d_in[3];
    const float* Eattr = (const float*)d_in[4];
    const float* AW = (const float*)d_in[6];
    const float* pe_g = (const float*)d_in[7];
    const float* pe_bt = (const float*)d_in[8];
    const float* pe_w = (const float*)d_in[9];
    const float* pe_b = (const float*)d_in[10];
    const float* gine_ew = (const float*)d_in[11];
    const float* gine_eb = (const float*)d_in[12];
    const float* gine_w1 = (const float*)d_in[13];
    const float* gine_b1 = (const float*)d_in[14];
    const float* gine_w2 = (const float*)d_in[15];
    const float* gine_b2 = (const float*)d_in[16];
    const float* wq = (const float*)d_in[17];
    const float* wk = (const float*)d_in[18];
    const float* wv = (const float*)d_in[19];
    const float* wo = (const float*)d_in[20];
    const float* bq = (const float*)d_in[21];
    const float* bk = (const float*)d_in[22];
    const float* bv = (const float*)d_in[23];
    const float* bo = (const float*)d_in[24];
    const float* n1g = (const float*)d_in[25];
    const float* n2g = (const float*)d_in[26];
    const float* n3g = (const float*)d_in[27];
    const float* n1b = (const float*)d_in[28];
    const float* n2b = (const float*)d_in[29];
    const float* n3b = (const float*)d_in[30];
    const float* mw1 = (const float*)d_in[31];
    const float* mb1 = (const float*)d_in[32];
    const float* mw2 = (const float*)d_in[33];
    const float* mb2 = (const float*)d_in[34];
    const float* ew1 = (const float*)d_in[35];
    const float* eb1 = (const float*)d_in[36];
    const float* ew2 = (const float*)d_in[37];
    const float* eb2 = (const float*)d_in[38];

    float* ws = (float*)d_ws;
    size_t off = 0;
    auto alloc = [&](size_t n) { float* p = ws + off; off += n; return p; };
    float* Aemb = alloc((size_t)EA * EEMB);
    float* Eemb = alloc((size_t)EE * EEMB);
    float* h = alloc((size_t)N_NODES * C);
    float* aggr = alloc((size_t)N_NODES * C);
    float* u = alloc((size_t)N_NODES * C);
    float* s1 = alloc((size_t)N_NODES * C);
    float* qb = alloc((size_t)N_NODES * C);
    float* kb = alloc((size_t)N_NODES * C);
    float* vb = alloc((size_t)N_NODES * C);
    float* ob = alloc((size_t)N_NODES * C);
    float* s2 = alloc((size_t)N_NODES * C);
    float* out3 = alloc((size_t)N_NODES * C);
    float* u2 = alloc((size_t)N_NODES * 176);
    float* stats = alloc(2048);
    float* st1 = stats;
    float* st2 = stats + 176;
    float* st3 = stats + 352;
    float* pe_mean = stats + 576;
    float* pe_rstd = stats + 608;

    const int NT = 256;
    const int nc_blocks = (N_NODES * C + NT - 1) / NT;
    const dim3 gA(512, 1, 1), gQKV(512, 1, 3), gU2(512, 2, 1);

    // --- prologue ---
    // 1536 blocks x 4 waves x 64 edges/wave = 393216 edges
    k_edge_emb5<<<1536, 256, 0, stream>>>(Aattr, Eattr, AW, Aemb, Eemb);
    k_colstats<<<PE_RAW, NT, 0, stream>>>(xd + XF, XD, N_NODES, pe_mean, pe_rstd);
    k_build_h<<<nc_blocks, NT, 0, stream>>>(xd, pe_mean, pe_rstd, pe_g, pe_bt, pe_w, pe_b, h);

    // --- layers ---
    for (int l = 0; l < NL; l++) {
        const float* ew = gine_ew + (size_t)l * EEMB * C;
        const float* eb = gine_eb + (size_t)l * C;
        const float* w1 = gine_w1 + (size_t)l * C * C;
        const float* b1 = gine_b1 + (size_t)l * C;
        const float* w2 = gine_w2 + (size_t)l * C * C;
        const float* b2 = gine_b2 + (size_t)l * C;
        const float* lwq = wq + (size_t)l * C * C;
        const float* lwk = wk + (size_t)l * C * C;
        const float* lwv = wv + (size_t)l * C * C;
        const float* lwo = wo + (size_t)l * C * C;
        const float* lbq = bq + (size_t)l * C;
        const float* lbk = bk + (size_t)l * C;
        const float* lbv = bv + (size_t)l * C;
        const float* lbo = bo + (size_t)l * C;
        const float* l1g = n1g + (size_t)l * C;
        const float* l1b = n1b + (size_t)l * C;
        const float* l2g = n2g + (size_t)l * C;
        const float* l2b = n2b + (size_t)l * C;
        const float* l3g = n3g + (size_t)l * C;
        const float* l3b = n3b + (size_t)l * C;
        const float* lmw1 = mw1 + (size_t)l * C * 176;
        const float* lmb1 = mb1 + (size_t)l * 176;
        const float* lmw2 = mw2 + (size_t)l * 176 * C;
        const float* lmb2 = mb2 + (size_t)l * C;

        hipMemsetAsync(aggr, 0, (size_t)N_NODES * C * sizeof(float), stream);
        hipMemsetAsync(stats, 0, 528 * sizeof(float), stream);
        k_gine_edge2<<<(EA * 22) / 256, 256, 0, stream>>>(Aemb, A_ei, h, ew, eb, aggr);
        // u = relu((h+aggr)@w1 + b1)
        k_gemm3<<<gA, 192, 0, stream>>>(h, aggr, C, w1, w1, w1, b1, b1, b1,
                                        u, u, u, C, C, 1, nullptr);
        // s1 = u@w2 + b2 + h  (+stats1)
        k_gemm3r<<<gA, 192, 0, stream>>>(u, C, w2, b2, h, s1, C, C, st1);
        // q,k,v fused via z
        k_gemm3<<<gQKV, 192, 0, stream>>>(h, nullptr, C, lwq, lwk, lwv, lbq, lbk, lbv,
                                          qb, kb, vb, C, C, 0, nullptr);
        k_attn<<<N_GRAPHS * NH * 4, 128, 0, stream>>>(qb, kb, vb, ob);
        // s2 = o@wo + bo + h  (+stats2)
        k_gemm3r<<<gA, 192, 0, stream>>>(ob, C, lwo, lbo, h, s2, C, C, st2);
        k_out3<<<nc_blocks, NT, 0, stream>>>(s1, s2, st1, st2, l1g, l1b, l2g, l2b, out3);
        // u2 = relu(out3@mw1 + mb1)   (176 cols -> y=2)
        k_gemm3<<<gU2, 192, 0, stream>>>(out3, nullptr, C, lmw1, lmw1, lmw1,
                                         lmb1, lmb1, lmb1, u2, u2, u2, 176, 176, 1, nullptr);
        // s3 = u2@mw2 + mb2 + out3  (+stats3)
        k_gemm3r<<<gA, 192, 0, stream>>>(u2, 176, lmw2, lmb2, out3, s1, C, C, st3);
        k_bn_apply<<<nc_blocks, NT, 0, stream>>>(s1, st3, l3g, l3b, h);
    }

    // --- epilogue: factored edge MLP ---
    k_gemm3r<<<gA, 192, 0, stream>>>(h, C, ew1, eb1, nullptr, qb, C, C, nullptr);                 // P
    k_gemm3r<<<gA, 192, 0, stream>>>(h, C, ew1 + (size_t)C * C, nullptr, nullptr, kb, C, C, nullptr); // Q
    k_final2<<<(EE * 64 + NT - 1) / NT, NT, 0, stream>>>(qb, kb, E_ei, Eemb,
                                                         ew1 + (size_t)2 * C * C, ew2, eb2,
                                                         (float*)d_out);
}

// Round 3
// 3548.574 us; speedup vs baseline: 1.2847x; 1.1375x over previous
//
#include <hip/hip_runtime.h>

#define N_NODES 16384
#define N_GRAPHS 32
#define NPG 512
#define C 88
#define NL 6
#define NH 4
#define HD 22
#define EA 131072
#define EE 262144
#define EDIM 197
#define EEMB 8
#define PE_RAW 18
#define PE_DIM 10
#define XD 96
#define XF 78
#define BN_EPS 1e-5f
#define ATT_SCALE 0.21320071635561044f
#define INV_N (1.0f / 16384.0f)
#define NROW (N_NODES * NH)   /* 65536 (q-row, head) rows */

// ---------------- edge attr embedding v5: 8 lanes/edge, j-split ------------
__global__ __launch_bounds__(256) void k_edge_emb5(const float* __restrict__ Aattr,
                                                   const float* __restrict__ Eattr,
                                                   const float* __restrict__ W,
                                                   float* __restrict__ Aemb,
                                                   float* __restrict__ Eemb) {
    __shared__ float Wt[8 * 204];
    int t = threadIdx.x;
    for (int idx = t; idx < EDIM * EEMB; idx += 256) {
        int k = idx >> 3, j = idx & 7;
        Wt[j * 204 + k] = W[idx];
    }
    __syncthreads();
    int wib = t >> 6, lane = t & 63;
    int e_loc = lane >> 3, j = lane & 7;
    const float* wrow = Wt + j * 204;
    long wbase = ((long)blockIdx.x * 4 + wib) * 64;
    for (int oct = 0; oct < 8; oct++) {
        long e = wbase + oct * 8 + e_loc;
        const float* attr;
        float* dst;
        if (e < EA) {
            attr = Aattr + e * EDIM;
            dst = Aemb + e * EEMB;
        } else {
            long q = e - EA;
            attr = Eattr + q * EDIM;
            dst = Eemb + q * EEMB;
        }
        float acc0 = 0.f, acc1 = 0.f;
#pragma unroll 7
        for (int i = 0; i < 49; i++) {
            float4 a = *(const float4*)(attr + 4 * i);
            float4 w = *(const float4*)(wrow + 4 * i);
            acc0 = fmaf(a.x, w.x, acc0);
            acc1 = fmaf(a.y, w.y, acc1);
            acc0 = fmaf(a.z, w.z, acc0);
            acc1 = fmaf(a.w, w.w, acc1);
        }
        acc0 += acc1;
        acc0 = fmaf(attr[196], wrow[196], acc0);
        dst[j] = acc0;
    }
}

// ---------------- per-column mean/rstd (only for the small PE BN) ----------
__global__ void k_colstats(const float* __restrict__ X, int ldx, int nrows,
                           float* __restrict__ mean, float* __restrict__ rstd) {
    int c = blockIdx.x;
    int t = threadIdx.x;
    float s = 0.f, s2 = 0.f;
    for (int r = t; r < nrows; r += 256) {
        float v = X[(size_t)r * ldx + c];
        s += v; s2 += v * v;
    }
    __shared__ float ls[256], ls2[256];
    ls[t] = s; ls2[t] = s2;
    __syncthreads();
    for (int off = 128; off > 0; off >>= 1) {
        if (t < off) { ls[t] += ls[t + off]; ls2[t] += ls2[t + off]; }
        __syncthreads();
    }
    if (t == 0) {
        float m = ls[0] / nrows;
        float var = ls2[0] / nrows - m * m;
        mean[c] = m;
        rstd[c] = rsqrtf(var + BN_EPS);
    }
}

// ---------------- build h0 = [x, bn(pe)@pe_w + pe_b] -----------------------
__global__ void k_build_h(const float* __restrict__ xd, const float* __restrict__ pe_mean,
                          const float* __restrict__ pe_rstd, const float* __restrict__ pe_g,
                          const float* __restrict__ pe_bt, const float* __restrict__ pe_w,
                          const float* __restrict__ pe_b, float* __restrict__ h) {
    int gid = blockIdx.x * blockDim.x + threadIdx.x;
    if (gid >= N_NODES * C) return;
    int n = gid / C, c = gid % C;
    float v;
    if (c < XF) {
        v = xd[(size_t)n * XD + c];
    } else {
        int j = c - XF;
        float acc = pe_b[j];
#pragma unroll
        for (int i = 0; i < PE_RAW; i++) {
            float pn = (xd[(size_t)n * XD + XF + i] - pe_mean[i]) * pe_rstd[i] * pe_g[i] + pe_bt[i];
            acc += pn * pe_w[i * PE_DIM + j];
        }
        v = acc;
    }
    h[gid] = v;
}

// ---------------- GINE edge message + scatter-add (quad version) -----------
__global__ void k_gine_edge2(const float* __restrict__ Aemb, const int* __restrict__ ei,
                             const float* __restrict__ h, const float* __restrict__ ew,
                             const float* __restrict__ eb, float* __restrict__ aggr) {
    int gid = blockIdx.x * blockDim.x + threadIdx.x;   // e*22 + q
    int e = gid / 22, q = gid % 22;
    const float* emb = Aemb + (size_t)e * EEMB;
    float4 acc = *(const float4*)(eb + 4 * q);
#pragma unroll
    for (int j = 0; j < EEMB; j++) {
        float ej = emb[j];
        float4 w = *(const float4*)(ew + j * C + 4 * q);
        acc.x = fmaf(ej, w.x, acc.x); acc.y = fmaf(ej, w.y, acc.y);
        acc.z = fmaf(ej, w.z, acc.z); acc.w = fmaf(ej, w.w, acc.w);
    }
    int s = ei[e], d = ei[EA + e];
    float4 hv = *(const float4*)(h + (size_t)s * C + 4 * q);
    float* ab = aggr + (size_t)d * C + 4 * q;
    float m0 = fmaxf(acc.x + hv.x, 0.f), m1 = fmaxf(acc.y + hv.y, 0.f);
    float m2 = fmaxf(acc.z + hv.z, 0.f), m3 = fmaxf(acc.w + hv.w, 0.f);
    atomicAdd(ab + 0, m0); atomicAdd(ab + 1, m1);
    atomicAdd(ab + 2, m2); atomicAdd(ab + 3, m3);
}

// ---------------- register-tiled GEMM, no LDS staging ----------------------
__global__ __launch_bounds__(192) void k_gemm3(const float* __restrict__ X,
                                               const float* __restrict__ X2, int K,
                                               const float* __restrict__ Wa,
                                               const float* __restrict__ Wb,
                                               const float* __restrict__ Wc,
                                               const float* __restrict__ ba,
                                               const float* __restrict__ bb,
                                               const float* __restrict__ bc,
                                               float* __restrict__ Oa,
                                               float* __restrict__ Ob,
                                               float* __restrict__ Oc,
                                               int ldw, int ldo, int relu,
                                               float* __restrict__ sums) {
    __shared__ float red[8 * 192];
    int t = threadIdx.x;
    int z = blockIdx.z;
    const float* W = (z == 0) ? Wa : (z == 1) ? Wb : Wc;
    const float* bias = (z == 0) ? ba : (z == 1) ? bb : bc;
    float* O = (z == 0) ? Oa : (z == 1) ? Ob : Oc;

    int cg = t % 24, nq = t / 24;
    int c4 = 4 * cg;
    int c_off = 88 * blockIdx.y;
    int cidx = c_off + c4;
    int loadc = cidx;
    if (loadc > ldw - 4) loadc = ldw - 4;
    int n0 = blockIdx.x * 32 + 4 * nq;
    const float* Xr = X + (size_t)n0 * K;
    const float* X2r = X2 ? X2 + (size_t)n0 * K : nullptr;

    float4 acc[4];
#pragma unroll
    for (int i = 0; i < 4; i++) acc[i] = make_float4(0.f, 0.f, 0.f, 0.f);

    for (int j = 0; j < K; j += 4) {
        const float* Wr = W + (size_t)j * ldw + loadc;
        float4 w0 = *(const float4*)(Wr);
        float4 w1 = *(const float4*)(Wr + ldw);
        float4 w2 = *(const float4*)(Wr + 2 * ldw);
        float4 w3 = *(const float4*)(Wr + 3 * ldw);
#pragma unroll
        for (int i = 0; i < 4; i++) {
            float4 x = *(const float4*)(Xr + (size_t)i * K + j);
            if (X2r) {
                float4 x2 = *(const float4*)(X2r + (size_t)i * K + j);
                x.x += x2.x; x.y += x2.y; x.z += x2.z; x.w += x2.w;
            }
            acc[i].x = fmaf(x.x, w0.x, acc[i].x); acc[i].y = fmaf(x.x, w0.y, acc[i].y);
            acc[i].z = fmaf(x.x, w0.z, acc[i].z); acc[i].w = fmaf(x.x, w0.w, acc[i].w);
            acc[i].x = fmaf(x.y, w1.x, acc[i].x); acc[i].y = fmaf(x.y, w1.y, acc[i].y);
            acc[i].z = fmaf(x.y, w1.z, acc[i].z); acc[i].w = fmaf(x.y, w1.w, acc[i].w);
            acc[i].x = fmaf(x.z, w2.x, acc[i].x); acc[i].y = fmaf(x.z, w2.y, acc[i].y);
            acc[i].z = fmaf(x.z, w2.z, acc[i].z); acc[i].w = fmaf(x.z, w2.w, acc[i].w);
            acc[i].x = fmaf(x.w, w3.x, acc[i].x); acc[i].y = fmaf(x.w, w3.y, acc[i].y);
            acc[i].z = fmaf(x.w, w3.z, acc[i].z); acc[i].w = fmaf(x.w, w3.w, acc[i].w);
        }
    }

    float4 bq = make_float4(0.f, 0.f, 0.f, 0.f);
    if (bias) bq = *(const float4*)(bias + loadc);
    float4 outv[4];
#pragma unroll
    for (int i = 0; i < 4; i++) {
        float4 v = acc[i];
        v.x += bq.x; v.y += bq.y; v.z += bq.z; v.w += bq.w;
        outv[i] = v;
    }
#pragma unroll
    for (int i = 0; i < 4; i++) {
        if (relu) {
            outv[i].x = fmaxf(outv[i].x, 0.f); outv[i].y = fmaxf(outv[i].y, 0.f);
            outv[i].z = fmaxf(outv[i].z, 0.f); outv[i].w = fmaxf(outv[i].w, 0.f);
        }
    }
    if (c4 < 88) {
#pragma unroll
        for (int i = 0; i < 4; i++)
            *(float4*)(O + (size_t)(n0 + i) * ldo + cidx) = outv[i];
    }
    if (sums) {
        float s[4] = {0.f, 0.f, 0.f, 0.f}, s2[4] = {0.f, 0.f, 0.f, 0.f};
#pragma unroll
        for (int i = 0; i < 4; i++) {
            s[0] += outv[i].x; s2[0] += outv[i].x * outv[i].x;
            s[1] += outv[i].y; s2[1] += outv[i].y * outv[i].y;
            s[2] += outv[i].z; s2[2] += outv[i].z * outv[i].z;
            s[3] += outv[i].w; s2[3] += outv[i].w * outv[i].w;
        }
        int base = nq * 192 + cg * 8;
#pragma unroll
        for (int k = 0; k < 4; k++) { red[base + k] = s[k]; red[base + 4 + k] = s2[k]; }
        __syncthreads();
        if (t < 96) {
            int g = t >> 2, o = t & 3;
            float a = 0.f, b = 0.f;
#pragma unroll
            for (int q = 0; q < 8; q++) {
                a += red[q * 192 + g * 8 + o];
                b += red[q * 192 + g * 8 + 4 + o];
            }
            int c = 4 * g + o;
            if (c < 88) {
                atomicAdd(&sums[c], a);
                atomicAdd(&sums[C + c], b);
            }
        }
    }
}

// residual add variant: OUT = X@W + b + R (uses same core, R applied)
__global__ __launch_bounds__(192) void k_gemm3r(const float* __restrict__ X, int K,
                                                const float* __restrict__ W,
                                                const float* __restrict__ bias,
                                                const float* __restrict__ R,
                                                float* __restrict__ O,
                                                int ldw, int ldo,
                                                float* __restrict__ sums) {
    __shared__ float red[8 * 192];
    int t = threadIdx.x;
    int cg = t % 24, nq = t / 24;
    int c4 = 4 * cg;
    int cidx = c4;
    int loadc = cidx;
    if (loadc > ldw - 4) loadc = ldw - 4;
    int n0 = blockIdx.x * 32 + 4 * nq;
    const float* Xr = X + (size_t)n0 * K;

    float4 acc[4];
#pragma unroll
    for (int i = 0; i < 4; i++) acc[i] = make_float4(0.f, 0.f, 0.f, 0.f);

    for (int j = 0; j < K; j += 4) {
        const float* Wr = W + (size_t)j * ldw + loadc;
        float4 w0 = *(const float4*)(Wr);
        float4 w1 = *(const float4*)(Wr + ldw);
        float4 w2 = *(const float4*)(Wr + 2 * ldw);
        float4 w3 = *(const float4*)(Wr + 3 * ldw);
#pragma unroll
        for (int i = 0; i < 4; i++) {
            float4 x = *(const float4*)(Xr + (size_t)i * K + j);
            acc[i].x = fmaf(x.x, w0.x, acc[i].x); acc[i].y = fmaf(x.x, w0.y, acc[i].y);
            acc[i].z = fmaf(x.x, w0.z, acc[i].z); acc[i].w = fmaf(x.x, w0.w, acc[i].w);
            acc[i].x = fmaf(x.y, w1.x, acc[i].x); acc[i].y = fmaf(x.y, w1.y, acc[i].y);
            acc[i].z = fmaf(x.y, w1.z, acc[i].z); acc[i].w = fmaf(x.y, w1.w, acc[i].w);
            acc[i].x = fmaf(x.z, w2.x, acc[i].x); acc[i].y = fmaf(x.z, w2.y, acc[i].y);
            acc[i].z = fmaf(x.z, w2.z, acc[i].z); acc[i].w = fmaf(x.z, w2.w, acc[i].w);
            acc[i].x = fmaf(x.w, w3.x, acc[i].x); acc[i].y = fmaf(x.w, w3.y, acc[i].y);
            acc[i].z = fmaf(x.w, w3.z, acc[i].z); acc[i].w = fmaf(x.w, w3.w, acc[i].w);
        }
    }

    float4 bq = make_float4(0.f, 0.f, 0.f, 0.f);
    if (bias) bq = *(const float4*)(bias + loadc);
    float4 outv[4];
#pragma unroll
    for (int i = 0; i < 4; i++) {
        float4 v = acc[i];
        v.x += bq.x; v.y += bq.y; v.z += bq.z; v.w += bq.w;
        if (R && c4 < 88) {
            float4 rv = *(const float4*)(R + (size_t)(n0 + i) * ldo + cidx);
            v.x += rv.x; v.y += rv.y; v.z += rv.z; v.w += rv.w;
        }
        outv[i] = v;
    }
    if (c4 < 88) {
#pragma unroll
        for (int i = 0; i < 4; i++)
            *(float4*)(O + (size_t)(n0 + i) * ldo + cidx) = outv[i];
    }
    if (sums) {
        float s[4] = {0.f, 0.f, 0.f, 0.f}, s2[4] = {0.f, 0.f, 0.f, 0.f};
#pragma unroll
        for (int i = 0; i < 4; i++) {
            s[0] += outv[i].x; s2[0] += outv[i].x * outv[i].x;
            s[1] += outv[i].y; s2[1] += outv[i].y * outv[i].y;
            s[2] += outv[i].z; s2[2] += outv[i].z * outv[i].z;
            s[3] += outv[i].w; s2[3] += outv[i].w * outv[i].w;
        }
        int base = nq * 192 + cg * 8;
#pragma unroll
        for (int k = 0; k < 4; k++) { red[base + k] = s[k]; red[base + 4 + k] = s2[k]; }
        __syncthreads();
        if (t < 96) {
            int g = t >> 2, o = t & 3;
            float a = 0.f, b = 0.f;
#pragma unroll
            for (int q = 0; q < 8; q++) {
                a += red[q * 192 + g * 8 + o];
                b += red[q * 192 + g * 8 + 4 + o];
            }
            int c = 4 * g + o;
            if (c < 88) {
                atomicAdd(&sums[c], a);
                atomicAdd(&sums[C + c], b);
            }
        }
    }
}

// ---------------- flash attention, 4-way split-K ---------------------------
// grid = (graph, qtile, head, split): 32*4*4*4 = 2048 blocks x 128 thr
// -> 4096 waves = 16 waves/CU = 4/SIMD (vs 1/SIMD unsplit: latency-bound).
// Each block: 128 q-rows vs keys [s*128, s*128+128). Writes UNNORMALIZED
// o-partial (22 floats/row) + (m, l) per row; exact LSE merge in k_attn_mg.
#define KCH 16
__global__ __launch_bounds__(128) void k_attn_sp(const float* __restrict__ q,
                                                 const float* __restrict__ kbuf,
                                                 const float* __restrict__ vbuf,
                                                 float* __restrict__ sp0,
                                                 float* __restrict__ sp1,
                                                 float* __restrict__ sp2,
                                                 float* __restrict__ sp3,
                                                 float* __restrict__ ml) {
    int bx = blockIdx.x;
    int s = bx & 3;
    int head = (bx >> 2) & 3;
    int qt = (bx >> 4) & 3;
    int g = bx >> 6;
    int t = threadIdx.x;
    int qnode = g * NPG + qt * 128 + t;
    float* spo = (s == 0) ? sp0 : (s == 1) ? sp1 : (s == 2) ? sp2 : sp3;
    const float* qr = q + (size_t)qnode * C + head * HD;
    float qreg[24], oreg[24];
#pragma unroll
    for (int d = 0; d < 24; d++) {
        qreg[d] = (d < HD) ? qr[d] * ATT_SCALE : 0.f;
        oreg[d] = 0.f;
    }
    float m = -1e30f, l = 0.f;
    __shared__ float Kt[64][24];
    __shared__ float Vt[64][24];
    for (int kt = s * 2; kt < s * 2 + 2; kt++) {
        __syncthreads();
        for (int idx = t; idx < 64 * HD; idx += 128) {
            int r = idx / HD, cc = idx % HD;
            int knode = g * NPG + kt * 64 + r;
            Kt[r][cc] = kbuf[(size_t)knode * C + head * HD + cc];
            Vt[r][cc] = vbuf[(size_t)knode * C + head * HD + cc];
        }
        for (int idx = t; idx < 64 * 2; idx += 128) {
            int r = idx >> 1, cc = HD + (idx & 1);
            Kt[r][cc] = 0.f; Vt[r][cc] = 0.f;
        }
        __syncthreads();
        for (int c0 = 0; c0 < 64; c0 += KCH) {
            float sc[KCH];
#pragma unroll
            for (int i = 0; i < KCH; i++) {
                float ss = 0.f;
#pragma unroll
                for (int d = 0; d < 24; d++) ss += qreg[d] * Kt[c0 + i][d];
                sc[i] = ss;
            }
            float tmax = sc[0];
#pragma unroll
            for (int i = 1; i < KCH; i++) tmax = fmaxf(tmax, sc[i]);
            float newm = fmaxf(m, tmax);
            float alpha = __expf(m - newm);
            l *= alpha;
#pragma unroll
            for (int d = 0; d < 24; d++) oreg[d] *= alpha;
            m = newm;
#pragma unroll
            for (int i = 0; i < KCH; i++) {
                float p = __expf(sc[i] - m);
                l += p;
#pragma unroll
                for (int d = 0; d < 24; d++) oreg[d] += p * Vt[c0 + i][d];
            }
        }
    }
    int row = qnode * NH + head;
    float* orow = spo + (size_t)row * HD;
#pragma unroll
    for (int d = 0; d < HD; d++) orow[d] = oreg[d];   // unnormalized partial
    ml[(size_t)s * NROW * 2 + row * 2] = m;
    ml[(size_t)s * NROW * 2 + row * 2 + 1] = l;
}

// exact log-sum-exp merge of 4 splits -> normalized o
__global__ void k_attn_mg(const float* __restrict__ sp0, const float* __restrict__ sp1,
                          const float* __restrict__ sp2, const float* __restrict__ sp3,
                          const float* __restrict__ ml, float* __restrict__ o) {
    int gid = blockIdx.x * blockDim.x + threadIdx.x;
    if (gid >= NROW * HD) return;
    int row = gid / HD, d = gid - row * HD;
    float m0 = ml[row * 2], l0 = ml[row * 2 + 1];
    float m1 = ml[(size_t)NROW * 2 + row * 2], l1 = ml[(size_t)NROW * 2 + row * 2 + 1];
    float m2 = ml[(size_t)NROW * 4 + row * 2], l2 = ml[(size_t)NROW * 4 + row * 2 + 1];
    float m3 = ml[(size_t)NROW * 6 + row * 2], l3 = ml[(size_t)NROW * 6 + row * 2 + 1];
    float mm = fmaxf(fmaxf(m0, m1), fmaxf(m2, m3));
    float w0 = __expf(m0 - mm), w1 = __expf(m1 - mm);
    float w2 = __expf(m2 - mm), w3 = __expf(m3 - mm);
    float L = l0 * w0 + l1 * w1 + l2 * w2 + l3 * w3;
    float num = sp0[gid] * w0 + sp1[gid] * w1 + sp2[gid] * w2 + sp3[gid] * w3;
    int qnode = row >> 2, head = row & 3;
    o[(size_t)qnode * C + head * HD + d] = num / L;
}

// ---------------- out3 = bn1(s1) + bn2(s2), stats from raw sums ------------
__global__ void k_out3(const float* __restrict__ s1, const float* __restrict__ s2,
                       const float* __restrict__ st1, const float* __restrict__ st2,
                       const float* __restrict__ g1, const float* __restrict__ b1,
                       const float* __restrict__ g2, const float* __restrict__ b2,
                       float* __restrict__ out3) {
    int gid = blockIdx.x * blockDim.x + threadIdx.x;
    if (gid >= N_NODES * C) return;
    int c = gid % C;
    float mu1 = st1[c] * INV_N;
    float r1 = rsqrtf(st1[C + c] * INV_N - mu1 * mu1 + BN_EPS);
    float mu2 = st2[c] * INV_N;
    float r2 = rsqrtf(st2[C + c] * INV_N - mu2 * mu2 + BN_EPS);
    float a = (s1[gid] - mu1) * r1 * g1[c] + b1[c];
    float b = (s2[gid] - mu2) * r2 * g2[c] + b2[c];
    out3[gid] = a + b;
}

// ---------------- h = bn3(s3), stats from raw sums -------------------------
__global__ void k_bn_apply(const float* __restrict__ s, const float* __restrict__ st,
                           const float* __restrict__ g, const float* __restrict__ b,
                           float* __restrict__ h) {
    int gid = blockIdx.x * blockDim.x + threadIdx.x;
    if (gid >= N_NODES * C) return;
    int c = gid % C;
    float mu = st[c] * INV_N;
    float r = rsqrtf(st[C + c] * INV_N - mu * mu + BN_EPS);
    h[gid] = (s[gid] - mu) * r * g[c] + b[c];
}

// ---------------- final: logit = relu(P[se]+Q[de]+Eemb@W1_emb) . w2 + b2 ---
__global__ void k_final2(const float* __restrict__ P, const float* __restrict__ Q,
                         const int* __restrict__ ei, const float* __restrict__ Eemb,
                         const float* __restrict__ w1emb, const float* __restrict__ w2,
                         const float* __restrict__ b2, float* __restrict__ out) {
    int wid = (blockIdx.x * blockDim.x + threadIdx.x) >> 6;
    int lane = threadIdx.x & 63;
    if (wid >= EE) return;
    int se = ei[wid], de = ei[EE + wid];
    const float* ps = P + (size_t)se * C;
    const float* qd = Q + (size_t)de * C;
    const float* em = Eemb + (size_t)wid * EEMB;
    float e0 = em[0], e1 = em[1], e2 = em[2], e3 = em[3];
    float e4 = em[4], e5 = em[5], e6 = em[6], e7 = em[7];
    int c1 = lane, c2 = lane + 64;
    bool has2 = (c2 < C);
    float a1 = ps[c1] + qd[c1];
    float a2 = has2 ? (ps[c2] + qd[c2]) : 0.f;
    a1 += e0 * w1emb[0 * C + c1] + e1 * w1emb[1 * C + c1] + e2 * w1emb[2 * C + c1] +
          e3 * w1emb[3 * C + c1] + e4 * w1emb[4 * C + c1] + e5 * w1emb[5 * C + c1] +
          e6 * w1emb[6 * C + c1] + e7 * w1emb[7 * C + c1];
    if (has2)
        a2 += e0 * w1emb[0 * C + c2] + e1 * w1emb[1 * C + c2] + e2 * w1emb[2 * C + c2] +
              e3 * w1emb[3 * C + c2] + e4 * w1emb[4 * C + c2] + e5 * w1emb[5 * C + c2] +
              e6 * w1emb[6 * C + c2] + e7 * w1emb[7 * C + c2];
    a1 = fmaxf(a1, 0.f);
    a2 = fmaxf(a2, 0.f);
    float part = a1 * w2[c1] + (has2 ? a2 * w2[c2] : 0.f);
#pragma unroll
    for (int off = 32; off > 0; off >>= 1) part += __shfl_xor(part, off, 64);
    if (lane == 0) out[wid] = part + b2[0];
}

// ===========================================================================
extern "C" void kernel_launch(void* const* d_in, const int* in_sizes, int n_in,
                              void* d_out, int out_size, void* d_ws, size_t ws_size,
                              hipStream_t stream) {
    const float* xd = (const float*)d_in[0];
    const int* A_ei = (const int*)d_in[1];
    const float* Aattr = (const float*)d_in[2];
    const int* E_ei = (const int*)d_in[3];
    const float* Eattr = (const float*)d_in[4];
    const float* AW = (const float*)d_in[6];
    const float* pe_g = (const float*)d_in[7];
    const float* pe_bt = (const float*)d_in[8];
    const float* pe_w = (const float*)d_in[9];
    const float* pe_b = (const float*)d_in[10];
    const float* gine_ew = (const float*)d_in[11];
    const float* gine_eb = (const float*)d_in[12];
    const float* gine_w1 = (const float*)d_in[13];
    const float* gine_b1 = (const float*)d_in[14];
    const float* gine_w2 = (const float*)d_in[15];
    const float* gine_b2 = (const float*)d_in[16];
    const float* wq = (const float*)d_in[17];
    const float* wk = (const float*)d_in[18];
    const float* wv = (const float*)d_in[19];
    const float* wo = (const float*)d_in[20];
    const float* bq = (const float*)d_in[21];
    const float* bk = (const float*)d_in[22];
    const float* bv = (const float*)d_in[23];
    const float* bo = (const float*)d_in[24];
    const float* n1g = (const float*)d_in[25];
    const float* n2g = (const float*)d_in[26];
    const float* n3g = (const float*)d_in[27];
    const float* n1b = (const float*)d_in[28];
    const float* n2b = (const float*)d_in[29];
    const float* n3b = (const float*)d_in[30];
    const float* mw1 = (const float*)d_in[31];
    const float* mb1 = (const float*)d_in[32];
    const float* mw2 = (const float*)d_in[33];
    const float* mb2 = (const float*)d_in[34];
    const float* ew1 = (const float*)d_in[35];
    const float* eb1 = (const float*)d_in[36];
    const float* ew2 = (const float*)d_in[37];
    const float* eb2 = (const float*)d_in[38];

    float* ws = (float*)d_ws;
    size_t off = 0;
    auto alloc = [&](size_t n) { float* p = ws + off; off += n; return p; };
    float* Aemb = alloc((size_t)EA * EEMB);
    float* Eemb = alloc((size_t)EE * EEMB);
    float* h = alloc((size_t)N_NODES * C);
    float* aggr = alloc((size_t)N_NODES * C);
    float* u = alloc((size_t)N_NODES * C);
    float* s1 = alloc((size_t)N_NODES * C);
    float* qb = alloc((size_t)N_NODES * C);
    float* kb = alloc((size_t)N_NODES * C);
    float* vb = alloc((size_t)N_NODES * C);
    float* ob = alloc((size_t)N_NODES * C);
    float* s2 = alloc((size_t)N_NODES * C);
    float* out3 = alloc((size_t)N_NODES * C);
    float* u2 = alloc((size_t)N_NODES * 176);
    float* stats = alloc(2048);
    float* st1 = stats;
    float* st2 = stats + 176;
    float* st3 = stats + 352;
    float* pe_mean = stats + 576;
    float* pe_rstd = stats + 608;

    // split-K attention scratch: all dead at attention time, each exactly N*C
    // sp0=aggr, sp1=u, sp2/sp3=u2 halves, (m,l)x4=s2 (needs 524288 <= N*C)
    float* sp0 = aggr;
    float* sp1 = u;
    float* sp2 = u2;
    float* sp3 = u2 + (size_t)N_NODES * C;
    float* mlb = s2;

    const int NT = 256;
    const int nc_blocks = (N_NODES * C + NT - 1) / NT;
    const dim3 gA(512, 1, 1), gQKV(512, 1, 3), gU2(512, 2, 1);

    // --- prologue ---
    k_edge_emb5<<<1536, 256, 0, stream>>>(Aattr, Eattr, AW, Aemb, Eemb);
    k_colstats<<<PE_RAW, NT, 0, stream>>>(xd + XF, XD, N_NODES, pe_mean, pe_rstd);
    k_build_h<<<nc_blocks, NT, 0, stream>>>(xd, pe_mean, pe_rstd, pe_g, pe_bt, pe_w, pe_b, h);

    // --- layers ---
    for (int l = 0; l < NL; l++) {
        const float* ew = gine_ew + (size_t)l * EEMB * C;
        const float* eb = gine_eb + (size_t)l * C;
        const float* w1 = gine_w1 + (size_t)l * C * C;
        const float* b1 = gine_b1 + (size_t)l * C;
        const float* w2 = gine_w2 + (size_t)l * C * C;
        const float* b2 = gine_b2 + (size_t)l * C;
        const float* lwq = wq + (size_t)l * C * C;
        const float* lwk = wk + (size_t)l * C * C;
        const float* lwv = wv + (size_t)l * C * C;
        const float* lwo = wo + (size_t)l * C * C;
        const float* lbq = bq + (size_t)l * C;
        const float* lbk = bk + (size_t)l * C;
        const float* lbv = bv + (size_t)l * C;
        const float* lbo = bo + (size_t)l * C;
        const float* l1g = n1g + (size_t)l * C;
        const float* l1b = n1b + (size_t)l * C;
        const float* l2g = n2g + (size_t)l * C;
        const float* l2b = n2b + (size_t)l * C;
        const float* l3g = n3g + (size_t)l * C;
        const float* l3b = n3b + (size_t)l * C;
        const float* lmw1 = mw1 + (size_t)l * C * 176;
        const float* lmb1 = mb1 + (size_t)l * 176;
        const float* lmw2 = mw2 + (size_t)l * 176 * C;
        const float* lmb2 = mb2 + (size_t)l * C;

        hipMemsetAsync(aggr, 0, (size_t)N_NODES * C * sizeof(float), stream);
        hipMemsetAsync(stats, 0, 528 * sizeof(float), stream);
        k_gine_edge2<<<(EA * 22) / 256, 256, 0, stream>>>(Aemb, A_ei, h, ew, eb, aggr);
        // u = relu((h+aggr)@w1 + b1)
        k_gemm3<<<gA, 192, 0, stream>>>(h, aggr, C, w1, w1, w1, b1, b1, b1,
                                        u, u, u, C, C, 1, nullptr);
        // s1 = u@w2 + b2 + h  (+stats1)
        k_gemm3r<<<gA, 192, 0, stream>>>(u, C, w2, b2, h, s1, C, C, st1);
        // q,k,v fused via z
        k_gemm3<<<gQKV, 192, 0, stream>>>(h, nullptr, C, lwq, lwk, lwv, lbq, lbk, lbv,
                                          qb, kb, vb, C, C, 0, nullptr);
        // split-K flash attention + exact merge (aggr/u/u2/s2 are dead here)
        k_attn_sp<<<N_GRAPHS * 4 * NH * 4, 128, 0, stream>>>(qb, kb, vb,
                                                             sp0, sp1, sp2, sp3, mlb);
        k_attn_mg<<<(NROW * HD + NT - 1) / NT, NT, 0, stream>>>(sp0, sp1, sp2, sp3, mlb, ob);
        // s2 = o@wo + bo + h  (+stats2)
        k_gemm3r<<<gA, 192, 0, stream>>>(ob, C, lwo, lbo, h, s2, C, C, st2);
        k_out3<<<nc_blocks, NT, 0, stream>>>(s1, s2, st1, st2, l1g, l1b, l2g, l2b, out3);
        // u2 = relu(out3@mw1 + mb1)   (176 cols -> y=2)
        k_gemm3<<<gU2, 192, 0, stream>>>(out3, nullptr, C, lmw1, lmw1, lmw1,
                                         lmb1, lmb1, lmb1, u2, u2, u2, 176, 176, 1, nullptr);
        // s3 = u2@mw2 + mb2 + out3  (+stats3)
        k_gemm3r<<<gA, 192, 0, stream>>>(u2, 176, lmw2, lmb2, out3, s1, C, C, st3);
        k_bn_apply<<<nc_blocks, NT, 0, stream>>>(s1, st3, l3g, l3b, h);
    }

    // --- epilogue: factored edge MLP ---
    k_gemm3r<<<gA, 192, 0, stream>>>(h, C, ew1, eb1, nullptr, qb, C, C, nullptr);                 // P
    k_gemm3r<<<gA, 192, 0, stream>>>(h, C, ew1 + (size_t)C * C, nullptr, nullptr, kb, C, C, nullptr); // Q
    k_final2<<<(EE * 64 + NT - 1) / NT, NT, 0, stream>>>(qb, kb, E_ei, Eemb,
                                                         ew1 + (size_t)2 * C * C, ew2, eb2,
                                                         (float*)d_out);
}

// Round 5
// 2643.514 us; speedup vs baseline: 1.7246x; 1.3424x over previous
//
#include <hip/hip_runtime.h>

#define N_NODES 16384
#define N_GRAPHS 32
#define NPG 512
#define C 88
#define NL 6
#define NH 4
#define HD 22
#define EA 131072
#define EE 262144
#define EDIM 197
#define EEMB 8
#define PE_RAW 18
#define PE_DIM 10
#define XD 96
#define XF 78
#define BN_EPS 1e-5f
#define ATT_SCALE 0.21320071635561044f
#define INV_N (1.0f / 16384.0f)
#define NROW (N_NODES * NH)   /* 65536 (q-row, head) rows */

// ---------------- edge attr embedding v5: 8 lanes/edge, j-split ------------
__global__ __launch_bounds__(256) void k_edge_emb5(const float* __restrict__ Aattr,
                                                   const float* __restrict__ Eattr,
                                                   const float* __restrict__ W,
                                                   float* __restrict__ Aemb,
                                                   float* __restrict__ Eemb) {
    __shared__ float Wt[8 * 204];
    int t = threadIdx.x;
    for (int idx = t; idx < EDIM * EEMB; idx += 256) {
        int k = idx >> 3, j = idx & 7;
        Wt[j * 204 + k] = W[idx];
    }
    __syncthreads();
    int wib = t >> 6, lane = t & 63;
    int e_loc = lane >> 3, j = lane & 7;
    const float* wrow = Wt + j * 204;
    long wbase = ((long)blockIdx.x * 4 + wib) * 64;
    for (int oct = 0; oct < 8; oct++) {
        long e = wbase + oct * 8 + e_loc;
        const float* attr;
        float* dst;
        if (e < EA) {
            attr = Aattr + e * EDIM;
            dst = Aemb + e * EEMB;
        } else {
            long q = e - EA;
            attr = Eattr + q * EDIM;
            dst = Eemb + q * EEMB;
        }
        float acc0 = 0.f, acc1 = 0.f;
#pragma unroll 7
        for (int i = 0; i < 49; i++) {
            float4 a = *(const float4*)(attr + 4 * i);
            float4 w = *(const float4*)(wrow + 4 * i);
            acc0 = fmaf(a.x, w.x, acc0);
            acc1 = fmaf(a.y, w.y, acc1);
            acc0 = fmaf(a.z, w.z, acc0);
            acc1 = fmaf(a.w, w.w, acc1);
        }
        acc0 += acc1;
        acc0 = fmaf(attr[196], wrow[196], acc0);
        dst[j] = acc0;
    }
}

// ---------------- per-column mean/rstd (only for the small PE BN) ----------
__global__ void k_colstats(const float* __restrict__ X, int ldx, int nrows,
                           float* __restrict__ mean, float* __restrict__ rstd) {
    int c = blockIdx.x;
    int t = threadIdx.x;
    float s = 0.f, s2 = 0.f;
    for (int r = t; r < nrows; r += 256) {
        float v = X[(size_t)r * ldx + c];
        s += v; s2 += v * v;
    }
    __shared__ float ls[256], ls2[256];
    ls[t] = s; ls2[t] = s2;
    __syncthreads();
    for (int off = 128; off > 0; off >>= 1) {
        if (t < off) { ls[t] += ls[t + off]; ls2[t] += ls2[t + off]; }
        __syncthreads();
    }
    if (t == 0) {
        float m = ls[0] / nrows;
        float var = ls2[0] / nrows - m * m;
        mean[c] = m;
        rstd[c] = rsqrtf(var + BN_EPS);
    }
}

// ---------------- build h0 = [x, bn(pe)@pe_w + pe_b] -----------------------
__global__ void k_build_h(const float* __restrict__ xd, const float* __restrict__ pe_mean,
                          const float* __restrict__ pe_rstd, const float* __restrict__ pe_g,
                          const float* __restrict__ pe_bt, const float* __restrict__ pe_w,
                          const float* __restrict__ pe_b, float* __restrict__ h) {
    int gid = blockIdx.x * blockDim.x + threadIdx.x;
    if (gid >= N_NODES * C) return;
    int n = gid / C, c = gid % C;
    float v;
    if (c < XF) {
        v = xd[(size_t)n * XD + c];
    } else {
        int j = c - XF;
        float acc = pe_b[j];
#pragma unroll
        for (int i = 0; i < PE_RAW; i++) {
            float pn = (xd[(size_t)n * XD + XF + i] - pe_mean[i]) * pe_rstd[i] * pe_g[i] + pe_bt[i];
            acc += pn * pe_w[i * PE_DIM + j];
        }
        v = acc;
    }
    h[gid] = v;
}

// ---------------- CSR-by-destination build (once; edge index is constant) --
__global__ void k_deg(const int* __restrict__ ei, int* __restrict__ deg) {
    int e = blockIdx.x * 256 + threadIdx.x;     // grid exact: 512*256 = EA
    atomicAdd(&deg[ei[EA + e]], 1);
}

// one block, 1024 threads, 16 entries/thread: exclusive scan of 16384 degs
__global__ __launch_bounds__(1024) void k_scan(const int* __restrict__ deg,
                                               int* __restrict__ offs,
                                               int* __restrict__ cur) {
    __shared__ int ps[1024];
    int t = threadIdx.x;
    int base = t * 16;
    int loc[16];
    int s = 0;
#pragma unroll
    for (int i = 0; i < 16; i++) { loc[i] = s; s += deg[base + i]; }
    ps[t] = s;
    __syncthreads();
    for (int off = 1; off < 1024; off <<= 1) {
        int v = (t >= off) ? ps[t - off] : 0;
        __syncthreads();
        ps[t] += v;
        __syncthreads();
    }
    int pre = (t == 0) ? 0 : ps[t - 1];
#pragma unroll
    for (int i = 0; i < 16; i++) {
        int o = pre + loc[i];
        offs[base + i] = o;
        cur[base + i] = o;
    }
    if (t == 1023) offs[16384] = ps[1023];
}

__global__ void k_csr_fill(const int* __restrict__ ei, int* __restrict__ cur,
                           int2* __restrict__ eidsrc) {
    int e = blockIdx.x * 256 + threadIdx.x;     // grid exact
    int d = ei[EA + e];
    int p = atomicAdd(&cur[d], 1);
    eidsrc[p] = make_int2(e, ei[e]);            // (edge id, src node)
}

// ---------------- GINE aggregation, gather form (no atomics) ---------------
// thread = (node, col-quad): walks incoming edges via CSR, recomputes
// ea = Aemb[e]@ew + eb in regs (VALU was 2.6% busy -> free), accumulates
// relu(h[src] + ea), plain store. Replaces 11.5M atomicAdds/layer (174us,
// 180MB write-through) with ~6MB of plain stores.
__global__ __launch_bounds__(256) void k_gine_gather(const float* __restrict__ Aemb,
                                                     const int* __restrict__ offs,
                                                     const int2* __restrict__ eidsrc,
                                                     const float* __restrict__ h,
                                                     const float* __restrict__ ew,
                                                     const float* __restrict__ eb,
                                                     float* __restrict__ aggr) {
    int gid = blockIdx.x * 256 + threadIdx.x;   // n*22 + q ; grid 1408 exact
    int n = gid / 22, q = gid - n * 22;
    float4 bse = *(const float4*)(eb + 4 * q);
    float w[8][4];
#pragma unroll
    for (int j = 0; j < 8; j++) {
        float4 wv = *(const float4*)(ew + j * C + 4 * q);
        w[j][0] = wv.x; w[j][1] = wv.y; w[j][2] = wv.z; w[j][3] = wv.w;
    }
    float4 acc = make_float4(0.f, 0.f, 0.f, 0.f);
    int i1 = offs[n + 1];
    for (int i = offs[n]; i < i1; i++) {
        int2 es = eidsrc[i];
        const float* emb = Aemb + (size_t)es.x * EEMB;
        float4 e0 = *(const float4*)(emb);
        float4 e1 = *(const float4*)(emb + 4);
        float4 hv = *(const float4*)(h + (size_t)es.y * C + 4 * q);
        float m0 = bse.x + hv.x, m1 = bse.y + hv.y;
        float m2 = bse.z + hv.z, m3 = bse.w + hv.w;
        m0 = fmaf(e0.x, w[0][0], m0); m1 = fmaf(e0.x, w[0][1], m1);
        m2 = fmaf(e0.x, w[0][2], m2); m3 = fmaf(e0.x, w[0][3], m3);
        m0 = fmaf(e0.y, w[1][0], m0); m1 = fmaf(e0.y, w[1][1], m1);
        m2 = fmaf(e0.y, w[1][2], m2); m3 = fmaf(e0.y, w[1][3], m3);
        m0 = fmaf(e0.z, w[2][0], m0); m1 = fmaf(e0.z, w[2][1], m1);
        m2 = fmaf(e0.z, w[2][2], m2); m3 = fmaf(e0.z, w[2][3], m3);
        m0 = fmaf(e0.w, w[3][0], m0); m1 = fmaf(e0.w, w[3][1], m1);
        m2 = fmaf(e0.w, w[3][2], m2); m3 = fmaf(e0.w, w[3][3], m3);
        m0 = fmaf(e1.x, w[4][0], m0); m1 = fmaf(e1.x, w[4][1], m1);
        m2 = fmaf(e1.x, w[4][2], m2); m3 = fmaf(e1.x, w[4][3], m3);
        m0 = fmaf(e1.y, w[5][0], m0); m1 = fmaf(e1.y, w[5][1], m1);
        m2 = fmaf(e1.y, w[5][2], m2); m3 = fmaf(e1.y, w[5][3], m3);
        m0 = fmaf(e1.z, w[6][0], m0); m1 = fmaf(e1.z, w[6][1], m1);
        m2 = fmaf(e1.z, w[6][2], m2); m3 = fmaf(e1.z, w[6][3], m3);
        m0 = fmaf(e1.w, w[7][0], m0); m1 = fmaf(e1.w, w[7][1], m1);
        m2 = fmaf(e1.w, w[7][2], m2); m3 = fmaf(e1.w, w[7][3], m3);
        acc.x += fmaxf(m0, 0.f); acc.y += fmaxf(m1, 0.f);
        acc.z += fmaxf(m2, 0.f); acc.w += fmaxf(m3, 0.f);
    }
    *(float4*)(aggr + (size_t)n * C + 4 * q) = acc;
}

// ---------------- register-tiled GEMM, no LDS staging ----------------------
__global__ __launch_bounds__(192) void k_gemm3(const float* __restrict__ X,
                                               const float* __restrict__ X2, int K,
                                               const float* __restrict__ Wa,
                                               const float* __restrict__ Wb,
                                               const float* __restrict__ Wc,
                                               const float* __restrict__ ba,
                                               const float* __restrict__ bb,
                                               const float* __restrict__ bc,
                                               float* __restrict__ Oa,
                                               float* __restrict__ Ob,
                                               float* __restrict__ Oc,
                                               int ldw, int ldo, int relu,
                                               float* __restrict__ sums) {
    __shared__ float red[8 * 192];
    int t = threadIdx.x;
    int z = blockIdx.z;
    const float* W = (z == 0) ? Wa : (z == 1) ? Wb : Wc;
    const float* bias = (z == 0) ? ba : (z == 1) ? bb : bc;
    float* O = (z == 0) ? Oa : (z == 1) ? Ob : Oc;

    int cg = t % 24, nq = t / 24;
    int c4 = 4 * cg;
    int c_off = 88 * blockIdx.y;
    int cidx = c_off + c4;
    int loadc = cidx;
    if (loadc > ldw - 4) loadc = ldw - 4;
    int n0 = blockIdx.x * 32 + 4 * nq;
    const float* Xr = X + (size_t)n0 * K;
    const float* X2r = X2 ? X2 + (size_t)n0 * K : nullptr;

    float4 acc[4];
#pragma unroll
    for (int i = 0; i < 4; i++) acc[i] = make_float4(0.f, 0.f, 0.f, 0.f);

    for (int j = 0; j < K; j += 4) {
        const float* Wr = W + (size_t)j * ldw + loadc;
        float4 w0 = *(const float4*)(Wr);
        float4 w1 = *(const float4*)(Wr + ldw);
        float4 w2 = *(const float4*)(Wr + 2 * ldw);
        float4 w3 = *(const float4*)(Wr + 3 * ldw);
#pragma unroll
        for (int i = 0; i < 4; i++) {
            float4 x = *(const float4*)(Xr + (size_t)i * K + j);
            if (X2r) {
                float4 x2 = *(const float4*)(X2r + (size_t)i * K + j);
                x.x += x2.x; x.y += x2.y; x.z += x2.z; x.w += x2.w;
            }
            acc[i].x = fmaf(x.x, w0.x, acc[i].x); acc[i].y = fmaf(x.x, w0.y, acc[i].y);
            acc[i].z = fmaf(x.x, w0.z, acc[i].z); acc[i].w = fmaf(x.x, w0.w, acc[i].w);
            acc[i].x = fmaf(x.y, w1.x, acc[i].x); acc[i].y = fmaf(x.y, w1.y, acc[i].y);
            acc[i].z = fmaf(x.y, w1.z, acc[i].z); acc[i].w = fmaf(x.y, w1.w, acc[i].w);
            acc[i].x = fmaf(x.z, w2.x, acc[i].x); acc[i].y = fmaf(x.z, w2.y, acc[i].y);
            acc[i].z = fmaf(x.z, w2.z, acc[i].z); acc[i].w = fmaf(x.z, w2.w, acc[i].w);
            acc[i].x = fmaf(x.w, w3.x, acc[i].x); acc[i].y = fmaf(x.w, w3.y, acc[i].y);
            acc[i].z = fmaf(x.w, w3.z, acc[i].z); acc[i].w = fmaf(x.w, w3.w, acc[i].w);
        }
    }

    float4 bq = make_float4(0.f, 0.f, 0.f, 0.f);
    if (bias) bq = *(const float4*)(bias + loadc);
    float4 outv[4];
#pragma unroll
    for (int i = 0; i < 4; i++) {
        float4 v = acc[i];
        v.x += bq.x; v.y += bq.y; v.z += bq.z; v.w += bq.w;
        outv[i] = v;
    }
#pragma unroll
    for (int i = 0; i < 4; i++) {
        if (relu) {
            outv[i].x = fmaxf(outv[i].x, 0.f); outv[i].y = fmaxf(outv[i].y, 0.f);
            outv[i].z = fmaxf(outv[i].z, 0.f); outv[i].w = fmaxf(outv[i].w, 0.f);
        }
    }
    if (c4 < 88) {
#pragma unroll
        for (int i = 0; i < 4; i++)
            *(float4*)(O + (size_t)(n0 + i) * ldo + cidx) = outv[i];
    }
    if (sums) {
        float s[4] = {0.f, 0.f, 0.f, 0.f}, s2[4] = {0.f, 0.f, 0.f, 0.f};
#pragma unroll
        for (int i = 0; i < 4; i++) {
            s[0] += outv[i].x; s2[0] += outv[i].x * outv[i].x;
            s[1] += outv[i].y; s2[1] += outv[i].y * outv[i].y;
            s[2] += outv[i].z; s2[2] += outv[i].z * outv[i].z;
            s[3] += outv[i].w; s2[3] += outv[i].w * outv[i].w;
        }
        int base = nq * 192 + cg * 8;
#pragma unroll
        for (int k = 0; k < 4; k++) { red[base + k] = s[k]; red[base + 4 + k] = s2[k]; }
        __syncthreads();
        if (t < 96) {
            int g = t >> 2, o = t & 3;
            float a = 0.f, b = 0.f;
#pragma unroll
            for (int q = 0; q < 8; q++) {
                a += red[q * 192 + g * 8 + o];
                b += red[q * 192 + g * 8 + 4 + o];
            }
            int c = 4 * g + o;
            if (c < 88) {
                atomicAdd(&sums[c], a);
                atomicAdd(&sums[C + c], b);
            }
        }
    }
}

// residual add variant: OUT = X@W + b + R (uses same core, R applied)
__global__ __launch_bounds__(192) void k_gemm3r(const float* __restrict__ X, int K,
                                                const float* __restrict__ W,
                                                const float* __restrict__ bias,
                                                const float* __restrict__ R,
                                                float* __restrict__ O,
                                                int ldw, int ldo,
                                                float* __restrict__ sums) {
    __shared__ float red[8 * 192];
    int t = threadIdx.x;
    int cg = t % 24, nq = t / 24;
    int c4 = 4 * cg;
    int cidx = c4;
    int loadc = cidx;
    if (loadc > ldw - 4) loadc = ldw - 4;
    int n0 = blockIdx.x * 32 + 4 * nq;
    const float* Xr = X + (size_t)n0 * K;

    float4 acc[4];
#pragma unroll
    for (int i = 0; i < 4; i++) acc[i] = make_float4(0.f, 0.f, 0.f, 0.f);

    for (int j = 0; j < K; j += 4) {
        const float* Wr = W + (size_t)j * ldw + loadc;
        float4 w0 = *(const float4*)(Wr);
        float4 w1 = *(const float4*)(Wr + ldw);
        float4 w2 = *(const float4*)(Wr + 2 * ldw);
        float4 w3 = *(const float4*)(Wr + 3 * ldw);
#pragma unroll
        for (int i = 0; i < 4; i++) {
            float4 x = *(const float4*)(Xr + (size_t)i * K + j);
            acc[i].x = fmaf(x.x, w0.x, acc[i].x); acc[i].y = fmaf(x.x, w0.y, acc[i].y);
            acc[i].z = fmaf(x.x, w0.z, acc[i].z); acc[i].w = fmaf(x.x, w0.w, acc[i].w);
            acc[i].x = fmaf(x.y, w1.x, acc[i].x); acc[i].y = fmaf(x.y, w1.y, acc[i].y);
            acc[i].z = fmaf(x.y, w1.z, acc[i].z); acc[i].w = fmaf(x.y, w1.w, acc[i].w);
            acc[i].x = fmaf(x.z, w2.x, acc[i].x); acc[i].y = fmaf(x.z, w2.y, acc[i].y);
            acc[i].z = fmaf(x.z, w2.z, acc[i].z); acc[i].w = fmaf(x.z, w2.w, acc[i].w);
            acc[i].x = fmaf(x.w, w3.x, acc[i].x); acc[i].y = fmaf(x.w, w3.y, acc[i].y);
            acc[i].z = fmaf(x.w, w3.z, acc[i].z); acc[i].w = fmaf(x.w, w3.w, acc[i].w);
        }
    }

    float4 bq = make_float4(0.f, 0.f, 0.f, 0.f);
    if (bias) bq = *(const float4*)(bias + loadc);
    float4 outv[4];
#pragma unroll
    for (int i = 0; i < 4; i++) {
        float4 v = acc[i];
        v.x += bq.x; v.y += bq.y; v.z += bq.z; v.w += bq.w;
        if (R && c4 < 88) {
            float4 rv = *(const float4*)(R + (size_t)(n0 + i) * ldo + cidx);
            v.x += rv.x; v.y += rv.y; v.z += rv.z; v.w += rv.w;
        }
        outv[i] = v;
    }
    if (c4 < 88) {
#pragma unroll
        for (int i = 0; i < 4; i++)
            *(float4*)(O + (size_t)(n0 + i) * ldo + cidx) = outv[i];
    }
    if (sums) {
        float s[4] = {0.f, 0.f, 0.f, 0.f}, s2[4] = {0.f, 0.f, 0.f, 0.f};
#pragma unroll
        for (int i = 0; i < 4; i++) {
            s[0] += outv[i].x; s2[0] += outv[i].x * outv[i].x;
            s[1] += outv[i].y; s2[1] += outv[i].y * outv[i].y;
            s[2] += outv[i].z; s2[2] += outv[i].z * outv[i].z;
            s[3] += outv[i].w; s2[3] += outv[i].w * outv[i].w;
        }
        int base = nq * 192 + cg * 8;
#pragma unroll
        for (int k = 0; k < 4; k++) { red[base + k] = s[k]; red[base + 4 + k] = s2[k]; }
        __syncthreads();
        if (t < 96) {
            int g = t >> 2, o = t & 3;
            float a = 0.f, b = 0.f;
#pragma unroll
            for (int q = 0; q < 8; q++) {
                a += red[q * 192 + g * 8 + o];
                b += red[q * 192 + g * 8 + 4 + o];
            }
            int c = 4 * g + o;
            if (c < 88) {
                atomicAdd(&sums[c], a);
                atomicAdd(&sums[C + c], b);
            }
        }
    }
}

// ---------------- flash attention, 4-way split-K ---------------------------
#define KCH 16
__global__ __launch_bounds__(128) void k_attn_sp(const float* __restrict__ q,
                                                 const float* __restrict__ kbuf,
                                                 const float* __restrict__ vbuf,
                                                 float* __restrict__ sp0,
                                                 float* __restrict__ sp1,
                                                 float* __restrict__ sp2,
                                                 float* __restrict__ sp3,
                                                 float* __restrict__ ml) {
    int bx = blockIdx.x;
    int s = bx & 3;
    int head = (bx >> 2) & 3;
    int qt = (bx >> 4) & 3;
    int g = bx >> 6;
    int t = threadIdx.x;
    int qnode = g * NPG + qt * 128 + t;
    float* spo = (s == 0) ? sp0 : (s == 1) ? sp1 : (s == 2) ? sp2 : sp3;
    const float* qr = q + (size_t)qnode * C + head * HD;
    float qreg[24], oreg[24];
#pragma unroll
    for (int d = 0; d < 24; d++) {
        qreg[d] = (d < HD) ? qr[d] * ATT_SCALE : 0.f;
        oreg[d] = 0.f;
    }
    float m = -1e30f, l = 0.f;
    __shared__ float Kt[64][24];
    __shared__ float Vt[64][24];
    for (int kt = s * 2; kt < s * 2 + 2; kt++) {
        __syncthreads();
        for (int idx = t; idx < 64 * HD; idx += 128) {
            int r = idx / HD, cc = idx % HD;
            int knode = g * NPG + kt * 64 + r;
            Kt[r][cc] = kbuf[(size_t)knode * C + head * HD + cc];
            Vt[r][cc] = vbuf[(size_t)knode * C + head * HD + cc];
        }
        for (int idx = t; idx < 64 * 2; idx += 128) {
            int r = idx >> 1, cc = HD + (idx & 1);
            Kt[r][cc] = 0.f; Vt[r][cc] = 0.f;
        }
        __syncthreads();
        for (int c0 = 0; c0 < 64; c0 += KCH) {
            float sc[KCH];
#pragma unroll
            for (int i = 0; i < KCH; i++) {
                float ss = 0.f;
#pragma unroll
                for (int d = 0; d < 24; d++) ss += qreg[d] * Kt[c0 + i][d];
                sc[i] = ss;
            }
            float tmax = sc[0];
#pragma unroll
            for (int i = 1; i < KCH; i++) tmax = fmaxf(tmax, sc[i]);
            float newm = fmaxf(m, tmax);
            float alpha = __expf(m - newm);
            l *= alpha;
#pragma unroll
            for (int d = 0; d < 24; d++) oreg[d] *= alpha;
            m = newm;
#pragma unroll
            for (int i = 0; i < KCH; i++) {
                float p = __expf(sc[i] - m);
                l += p;
#pragma unroll
                for (int d = 0; d < 24; d++) oreg[d] += p * Vt[c0 + i][d];
            }
        }
    }
    int row = qnode * NH + head;
    float* orow = spo + (size_t)row * HD;
#pragma unroll
    for (int d = 0; d < HD; d++) orow[d] = oreg[d];   // unnormalized partial
    ml[(size_t)s * NROW * 2 + row * 2] = m;
    ml[(size_t)s * NROW * 2 + row * 2 + 1] = l;
}

// exact log-sum-exp merge of 4 splits -> normalized o
__global__ void k_attn_mg(const float* __restrict__ sp0, const float* __restrict__ sp1,
                          const float* __restrict__ sp2, const float* __restrict__ sp3,
                          const float* __restrict__ ml, float* __restrict__ o) {
    int gid = blockIdx.x * blockDim.x + threadIdx.x;
    if (gid >= NROW * HD) return;
    int row = gid / HD, d = gid - row * HD;
    float m0 = ml[row * 2], l0 = ml[row * 2 + 1];
    float m1 = ml[(size_t)NROW * 2 + row * 2], l1 = ml[(size_t)NROW * 2 + row * 2 + 1];
    float m2 = ml[(size_t)NROW * 4 + row * 2], l2 = ml[(size_t)NROW * 4 + row * 2 + 1];
    float m3 = ml[(size_t)NROW * 6 + row * 2], l3 = ml[(size_t)NROW * 6 + row * 2 + 1];
    float mm = fmaxf(fmaxf(m0, m1), fmaxf(m2, m3));
    float w0 = __expf(m0 - mm), w1 = __expf(m1 - mm);
    float w2 = __expf(m2 - mm), w3 = __expf(m3 - mm);
    float L = l0 * w0 + l1 * w1 + l2 * w2 + l3 * w3;
    float num = sp0[gid] * w0 + sp1[gid] * w1 + sp2[gid] * w2 + sp3[gid] * w3;
    int qnode = row >> 2, head = row & 3;
    o[(size_t)qnode * C + head * HD + d] = num / L;
}

// ---------------- out3 = bn1(s1) + bn2(s2), stats from raw sums ------------
__global__ void k_out3(const float* __restrict__ s1, const float* __restrict__ s2,
                       const float* __restrict__ st1, const float* __restrict__ st2,
                       const float* __restrict__ g1, const float* __restrict__ b1,
                       const float* __restrict__ g2, const float* __restrict__ b2,
                       float* __restrict__ out3) {
    int gid = blockIdx.x * blockDim.x + threadIdx.x;
    if (gid >= N_NODES * C) return;
    int c = gid % C;
    float mu1 = st1[c] * INV_N;
    float r1 = rsqrtf(st1[C + c] * INV_N - mu1 * mu1 + BN_EPS);
    float mu2 = st2[c] * INV_N;
    float r2 = rsqrtf(st2[C + c] * INV_N - mu2 * mu2 + BN_EPS);
    float a = (s1[gid] - mu1) * r1 * g1[c] + b1[c];
    float b = (s2[gid] - mu2) * r2 * g2[c] + b2[c];
    out3[gid] = a + b;
}

// ---------------- h = bn3(s3), stats from raw sums -------------------------
__global__ void k_bn_apply(const float* __restrict__ s, const float* __restrict__ st,
                           const float* __restrict__ g, const float* __restrict__ b,
                           float* __restrict__ h) {
    int gid = blockIdx.x * blockDim.x + threadIdx.x;
    if (gid >= N_NODES * C) return;
    int c = gid % C;
    float mu = st[c] * INV_N;
    float r = rsqrtf(st[C + c] * INV_N - mu * mu + BN_EPS);
    h[gid] = (s[gid] - mu) * r * g[c] + b[c];
}

// ---------------- final: logit = relu(P[se]+Q[de]+Eemb@W1_emb) . w2 + b2 ---
__global__ void k_final2(const float* __restrict__ P, const float* __restrict__ Q,
                         const int* __restrict__ ei, const float* __restrict__ Eemb,
                         const float* __restrict__ w1emb, const float* __restrict__ w2,
                         const float* __restrict__ b2, float* __restrict__ out) {
    int wid = (blockIdx.x * blockDim.x + threadIdx.x) >> 6;
    int lane = threadIdx.x & 63;
    if (wid >= EE) return;
    int se = ei[wid], de = ei[EE + wid];
    const float* ps = P + (size_t)se * C;
    const float* qd = Q + (size_t)de * C;
    const float* em = Eemb + (size_t)wid * EEMB;
    float e0 = em[0], e1 = em[1], e2 = em[2], e3 = em[3];
    float e4 = em[4], e5 = em[5], e6 = em[6], e7 = em[7];
    int c1 = lane, c2 = lane + 64;
    bool has2 = (c2 < C);
    float a1 = ps[c1] + qd[c1];
    float a2 = has2 ? (ps[c2] + qd[c2]) : 0.f;
    a1 += e0 * w1emb[0 * C + c1] + e1 * w1emb[1 * C + c1] + e2 * w1emb[2 * C + c1] +
          e3 * w1emb[3 * C + c1] + e4 * w1emb[4 * C + c1] + e5 * w1emb[5 * C + c1] +
          e6 * w1emb[6 * C + c1] + e7 * w1emb[7 * C + c1];
    if (has2)
        a2 += e0 * w1emb[0 * C + c2] + e1 * w1emb[1 * C + c2] + e2 * w1emb[2 * C + c2] +
              e3 * w1emb[3 * C + c2] + e4 * w1emb[4 * C + c2] + e5 * w1emb[5 * C + c2] +
              e6 * w1emb[6 * C + c2] + e7 * w1emb[7 * C + c2];
    a1 = fmaxf(a1, 0.f);
    a2 = fmaxf(a2, 0.f);
    float part = a1 * w2[c1] + (has2 ? a2 * w2[c2] : 0.f);
#pragma unroll
    for (int off = 32; off > 0; off >>= 1) part += __shfl_xor(part, off, 64);
    if (lane == 0) out[wid] = part + b2[0];
}

// ===========================================================================
extern "C" void kernel_launch(void* const* d_in, const int* in_sizes, int n_in,
                              void* d_out, int out_size, void* d_ws, size_t ws_size,
                              hipStream_t stream) {
    const float* xd = (const float*)d_in[0];
    const int* A_ei = (const int*)d_in[1];
    const float* Aattr = (const float*)d_in[2];
    const int* E_ei = (const int*)d_in[3];
    const float* Eattr = (const float*)d_in[4];
    const float* AW = (const float*)d_in[6];
    const float* pe_g = (const float*)d_in[7];
    const float* pe_bt = (const float*)d_in[8];
    const float* pe_w = (const float*)d_in[9];
    const float* pe_b = (const float*)d_in[10];
    const float* gine_ew = (const float*)d_in[11];
    const float* gine_eb = (const float*)d_in[12];
    const float* gine_w1 = (const float*)d_in[13];
    const float* gine_b1 = (const float*)d_in[14];
    const float* gine_w2 = (const float*)d_in[15];
    const float* gine_b2 = (const float*)d_in[16];
    const float* wq = (const float*)d_in[17];
    const float* wk = (const float*)d_in[18];
    const float* wv = (const float*)d_in[19];
    const float* wo = (const float*)d_in[20];
    const float* bq = (const float*)d_in[21];
    const float* bk = (const float*)d_in[22];
    const float* bv = (const float*)d_in[23];
    const float* bo = (const float*)d_in[24];
    const float* n1g = (const float*)d_in[25];
    const float* n2g = (const float*)d_in[26];
    const float* n3g = (const float*)d_in[27];
    const float* n1b = (const float*)d_in[28];
    const float* n2b = (const float*)d_in[29];
    const float* n3b = (const float*)d_in[30];
    const float* mw1 = (const float*)d_in[31];
    const float* mb1 = (const float*)d_in[32];
    const float* mw2 = (const float*)d_in[33];
    const float* mb2 = (const float*)d_in[34];
    const float* ew1 = (const float*)d_in[35];
    const float* eb1 = (const float*)d_in[36];
    const float* ew2 = (const float*)d_in[37];
    const float* eb2 = (const float*)d_in[38];

    float* ws = (float*)d_ws;
    size_t off = 0;
    auto alloc = [&](size_t n) { float* p = ws + off; off += n; return p; };
    float* Aemb = alloc((size_t)EA * EEMB);
    float* Eemb = alloc((size_t)EE * EEMB);
    float* h = alloc((size_t)N_NODES * C);
    float* aggr = alloc((size_t)N_NODES * C);
    float* u = alloc((size_t)N_NODES * C);
    float* s1 = alloc((size_t)N_NODES * C);
    float* qb = alloc((size_t)N_NODES * C);
    float* kb = alloc((size_t)N_NODES * C);
    float* vb = alloc((size_t)N_NODES * C);
    float* ob = alloc((size_t)N_NODES * C);
    float* s2 = alloc((size_t)N_NODES * C);
    float* out3 = alloc((size_t)N_NODES * C);
    float* u2 = alloc((size_t)N_NODES * 176);
    float* stats = alloc(2048);
    float* st1 = stats;
    float* st2 = stats + 176;
    float* st3 = stats + 352;
    float* pe_mean = stats + 576;
    float* pe_rstd = stats + 608;
    // CSR-by-destination for the GINE aggregation (built once; ints in ws)
    int* ideg = (int*)alloc(16384);
    int* ioffs = (int*)alloc(16512);
    int* icur = (int*)alloc(16384);
    int2* ieid = (int2*)alloc(2 * EA);      // (edge, src) pairs; 8B-aligned

    // split-K attention scratch: all dead at attention time, each exactly N*C
    float* sp0 = aggr;
    float* sp1 = u;
    float* sp2 = u2;
    float* sp3 = u2 + (size_t)N_NODES * C;
    float* mlb = s2;

    const int NT = 256;
    const int nc_blocks = (N_NODES * C + NT - 1) / NT;
    const dim3 gA(512, 1, 1), gQKV(512, 1, 3), gU2(512, 2, 1);

    // --- prologue ---
    k_edge_emb5<<<1536, 256, 0, stream>>>(Aattr, Eattr, AW, Aemb, Eemb);
    k_colstats<<<PE_RAW, NT, 0, stream>>>(xd + XF, XD, N_NODES, pe_mean, pe_rstd);
    k_build_h<<<nc_blocks, NT, 0, stream>>>(xd, pe_mean, pe_rstd, pe_g, pe_bt, pe_w, pe_b, h);
    // CSR build (edge index constant across layers)
    hipMemsetAsync(ideg, 0, 16384 * sizeof(int), stream);
    k_deg<<<512, 256, 0, stream>>>(A_ei, ideg);
    k_scan<<<1, 1024, 0, stream>>>(ideg, ioffs, icur);
    k_csr_fill<<<512, 256, 0, stream>>>(A_ei, icur, ieid);

    // --- layers ---
    for (int l = 0; l < NL; l++) {
        const float* ew = gine_ew + (size_t)l * EEMB * C;
        const float* eb = gine_eb + (size_t)l * C;
        const float* w1 = gine_w1 + (size_t)l * C * C;
        const float* b1 = gine_b1 + (size_t)l * C;
        const float* w2 = gine_w2 + (size_t)l * C * C;
        const float* b2 = gine_b2 + (size_t)l * C;
        const float* lwq = wq + (size_t)l * C * C;
        const float* lwk = wk + (size_t)l * C * C;
        const float* lwv = wv + (size_t)l * C * C;
        const float* lwo = wo + (size_t)l * C * C;
        const float* lbq = bq + (size_t)l * C;
        const float* lbk = bk + (size_t)l * C;
        const float* lbv = bv + (size_t)l * C;
        const float* lbo = bo + (size_t)l * C;
        const float* l1g = n1g + (size_t)l * C;
        const float* l1b = n1b + (size_t)l * C;
        const float* l2g = n2g + (size_t)l * C;
        const float* l2b = n2b + (size_t)l * C;
        const float* l3g = n3g + (size_t)l * C;
        const float* l3b = n3b + (size_t)l * C;
        const float* lmw1 = mw1 + (size_t)l * C * 176;
        const float* lmb1 = mb1 + (size_t)l * 176;
        const float* lmw2 = mw2 + (size_t)l * 176 * C;
        const float* lmb2 = mb2 + (size_t)l * C;

        hipMemsetAsync(stats, 0, 528 * sizeof(float), stream);
        // aggr = segment_sum(relu(h[src]+ea), dst)  -- gather form, no atomics
        k_gine_gather<<<(N_NODES * 22) / 256, 256, 0, stream>>>(Aemb, ioffs, ieid,
                                                                h, ew, eb, aggr);
        // u = relu((h+aggr)@w1 + b1)
        k_gemm3<<<gA, 192, 0, stream>>>(h, aggr, C, w1, w1, w1, b1, b1, b1,
                                        u, u, u, C, C, 1, nullptr);
        // s1 = u@w2 + b2 + h  (+stats1)
        k_gemm3r<<<gA, 192, 0, stream>>>(u, C, w2, b2, h, s1, C, C, st1);
        // q,k,v fused via z
        k_gemm3<<<gQKV, 192, 0, stream>>>(h, nullptr, C, lwq, lwk, lwv, lbq, lbk, lbv,
                                          qb, kb, vb, C, C, 0, nullptr);
        // split-K flash attention + exact merge (aggr/u/u2/s2 are dead here)
        k_attn_sp<<<N_GRAPHS * 4 * NH * 4, 128, 0, stream>>>(qb, kb, vb,
                                                             sp0, sp1, sp2, sp3, mlb);
        k_attn_mg<<<(NROW * HD + NT - 1) / NT, NT, 0, stream>>>(sp0, sp1, sp2, sp3, mlb, ob);
        // s2 = o@wo + bo + h  (+stats2)
        k_gemm3r<<<gA, 192, 0, stream>>>(ob, C, lwo, lbo, h, s2, C, C, st2);
        k_out3<<<nc_blocks, NT, 0, stream>>>(s1, s2, st1, st2, l1g, l1b, l2g, l2b, out3);
        // u2 = relu(out3@mw1 + mb1)   (176 cols -> y=2)
        k_gemm3<<<gU2, 192, 0, stream>>>(out3, nullptr, C, lmw1, lmw1, lmw1,
                                         lmb1, lmb1, lmb1, u2, u2, u2, 176, 176, 1, nullptr);
        // s3 = u2@mw2 + mb2 + out3  (+stats3)
        k_gemm3r<<<gA, 192, 0, stream>>>(u2, 176, lmw2, lmb2, out3, s1, C, C, st3);
        k_bn_apply<<<nc_blocks, NT, 0, stream>>>(s1, st3, l3g, l3b, h);
    }

    // --- epilogue: factored edge MLP ---
    k_gemm3r<<<gA, 192, 0, stream>>>(h, C, ew1, eb1, nullptr, qb, C, C, nullptr);                 // P
    k_gemm3r<<<gA, 192, 0, stream>>>(h, C, ew1 + (size_t)C * C, nullptr, nullptr, kb, C, C, nullptr); // Q
    k_final2<<<(EE * 64 + NT - 1) / NT, NT, 0, stream>>>(qb, kb, E_ei, Eemb,
                                                         ew1 + (size_t)2 * C * C, ew2, eb2,
                                                         (float*)d_out);
}